// Round 12
// baseline (1400.390 us; speedup 1.0000x reference)
//
#include <hip/hip_runtime.h>
#include <math.h>

#define B_ 16
#define N_ 512
#define D_ 32
#define E_ 8176
#define SLEFT_ 16384
#define FSS_ 601
#define BN_ (B_*N_)            // 8192
#define BE_ (B_*E_)            // 130816
#define NSROW_ (SLEFT_ + 2*E_) // 32736
#define OUT_R_ (B_*FSS_)       // 9616
#define HLD_ 768               // combined width: reward 0..639, next 640..767

typedef __attribute__((ext_vector_type(8))) short short8;
typedef __attribute__((ext_vector_type(4))) float f32x4;

typedef __attribute__((address_space(3))) uint lds_uint;
typedef __attribute__((address_space(1))) const uint g_uint;

__device__ __forceinline__ void gl_lds16(const ushort* gp, ushort* lp) {
  __builtin_amdgcn_global_load_lds((g_uint*)gp, (lds_uint*)lp, 16, 0, 0);
}

__device__ __forceinline__ ushort f2b(float f) {
  uint u = __builtin_bit_cast(uint, f);
  u += 0x7FFFu + ((u >> 16) & 1u);
  return (ushort)(u >> 16);
}
__device__ __forceinline__ float b2f(ushort h) {
  return __builtin_bit_cast(float, ((uint)h) << 16);
}

// ---------------- index / CSR build ----------------

__global__ __launch_bounds__(256) void k_indices(const float* __restrict__ ns,
                                                 int* __restrict__ src_i,
                                                 int* __restrict__ dst_i,
                                                 int* __restrict__ cnt) {
  int idx = blockIdx.x*256 + threadIdx.x;
  if (idx >= BE_) return;
  int b = idx / E_;
  int j = idx - b*E_;
  const float* row = ns + (size_t)b*NSROW_;
  int s = (int)row[SLEFT_ + j];
  int r = (int)row[SLEFT_ + E_ + j];
  src_i[idx] = b*N_ + s;
  int dst = b*N_ + r;
  dst_i[idx] = dst;
  atomicAdd(&cnt[dst], 1);
}

__global__ __launch_bounds__(1024) void k_scan(const int* __restrict__ cnt,
                                               int* __restrict__ rowptr) {
  __shared__ int part[1024];
  int t = threadIdx.x;
  int base = t*8;
  int loc[8]; int s = 0;
  #pragma unroll
  for (int i=0;i<8;i++){ loc[i]=cnt[base+i]; s+=loc[i]; }
  part[t]=s; __syncthreads();
  for (int off=1; off<1024; off<<=1) {
    int v = (t>=off)?part[t-off]:0;
    __syncthreads();
    part[t]+=v;
    __syncthreads();
  }
  int ex = (t==0)?0:part[t-1];
  #pragma unroll
  for (int i=0;i<8;i++){ rowptr[base+i]=ex; ex+=loc[i]; }
  if (t==1023) rowptr[BN_]=ex;
}

__global__ __launch_bounds__(256) void k_scatter(const int* __restrict__ src_i,
                                                 const int* __restrict__ dst_i,
                                                 const int* __restrict__ rowptr,
                                                 int* __restrict__ fill,
                                                 int* __restrict__ csr_src) {
  int idx = blockIdx.x*256+threadIdx.x;
  if (idx>=BE_) return;
  int dst = dst_i[idx];
  int pos = rowptr[dst] + atomicAdd(&fill[dst],1);
  csr_src[pos] = src_i[idx];
}

// ---------------- sa (bf16, padded to K=64) ----------------

__global__ __launch_bounds__(256) void k_sa(const float* __restrict__ ns,
                                            const int* __restrict__ a,
                                            ushort* __restrict__ sa) {
  int idx = blockIdx.x*256+threadIdx.x;
  if (idx >= BN_*64) return;
  int v = idx >> 6, c = idx & 63;
  int b = v >> 9, n = v & 511;
  float val = 0.f;
  if (c < 32)       val = ns[(size_t)b*NSROW_ + n*32 + c];
  else if (c == 32) val = (a[b]==n) ? 1.f : 0.f;
  sa[idx] = f2b(val);
}

// ---------------- LDS-tiled block-diagonal weight transpose ---------------

struct WtP { const float* Wr[4]; const float* Wn[4]; ushort* T[4]; };

__global__ __launch_bounds__(256) void k_wt_tr(WtP p) {
  int t = blockIdx.x;
  int s, base, KP, DINR, DINN, DOUTN, KOFF;
  if (t < 48)        { s=0; base=0;    KP=64;  DINR=33;  DINN=33;  DOUTN=128; KOFF=0;   }
  else if (t < 600)  { s=1; base=48;   KP=736; DINR=601; DINN=128; DOUTN=64;  KOFF=608; }
  else if (t < 1104) { s=2; base=600;  KP=672; DINR=601; DINN=64;  DOUTN=64;  KOFF=608; }
  else               { s=3; base=1104; KP=672; DINR=601; DINN=64;  DOUTN=32;  KOFF=608; }
  int ti = t - base;
  int kt = ti / 24, nt = ti - kt*24;
  int k0 = kt*32, n0 = nt*32;
  __shared__ float tile[32][33];
  int tid = threadIdx.x;
  int cc = tid & 31, rr = tid >> 5;
  #pragma unroll
  for (int it=0; it<4; it++) {
    int k = k0 + it*8 + rr;
    int n = n0 + cc;
    float v = 0.f;
    if (n < 640) { if (n < 601 && k < DINR) v = p.Wr[s][(size_t)k*601 + n]; }
    else { int nn = n-640, kk = k-KOFF;
           if (nn < DOUTN && kk >= 0 && kk < DINN) v = p.Wn[s][(size_t)kk*DOUTN + nn]; }
    tile[it*8+rr][cc] = v;
  }
  __syncthreads();
  #pragma unroll
  for (int it=0; it<4; it++) {
    int n = n0 + it*8 + rr;
    int k = k0 + cc;
    p.T[s][(size_t)n*KP + k] = f2b(tile[cc][it*8+rr]);
  }
}

// ---------------- MFMA bf16 GEMM, 64x128 tile + atomic es/ed epilogue -----

__global__ __launch_bounds__(256) void k_gemm(const ushort* __restrict__ A,
                                              const ushort* __restrict__ Bt,
                                              ushort* __restrict__ C,
                                              float* __restrict__ esed, // es_r|ed_r|es_n|ed_n
                                              const float* __restrict__ asr,
                                              const float* __restrict__ adr,
                                              const float* __restrict__ asn,
                                              const float* __restrict__ adn,
                                              int Kpad, int dn) {
  __shared__ ushort Asm[64*32];
  __shared__ ushort Bsm[128*32];
  int tid = threadIdx.x;
  int rowBase = blockIdx.y * 64;
  int colBase = blockIdx.x * 128;
  int wave = tid >> 6, lane = tid & 63;
  int wr = (wave >> 1) * 32, wc = (wave & 1) * 64;
  int lm = lane & 15, lk = (lane >> 4) * 8;

  f32x4 acc[2][4];
  #pragma unroll
  for (int i=0;i<2;i++)
    #pragma unroll
    for (int j=0;j<4;j++) acc[i][j] = (f32x4){0.f,0.f,0.f,0.f};

  int t0 = tid, t1 = tid + 256;
  const ushort* Ag0 = A  + (size_t)(rowBase + (t0>>2))*Kpad + (t0&3)*8;
  const ushort* Bg0 = Bt + (size_t)(colBase + (t0>>2))*Kpad + (t0&3)*8;
  const ushort* Bg1 = Bt + (size_t)(colBase + (t1>>2))*Kpad + (t1&3)*8;
  ushort* Al0 = &Asm[t0*8];
  ushort* Bl0 = &Bsm[t0*8];
  ushort* Bl1 = &Bsm[t1*8];

  for (int k0 = 0; k0 < Kpad; k0 += 32) {
    gl_lds16(Ag0 + k0, Al0);
    gl_lds16(Bg0 + k0, Bl0);
    gl_lds16(Bg1 + k0, Bl1);
    __syncthreads();
    short8 af[2], bfr[4];
    #pragma unroll
    for (int i=0;i<2;i++) af[i]  = *(short8*)&Asm[(wr + i*16 + lm)*32 + lk];
    #pragma unroll
    for (int j=0;j<4;j++) bfr[j] = *(short8*)&Bsm[(wc + j*16 + lm)*32 + lk];
    #pragma unroll
    for (int i=0;i<2;i++)
      #pragma unroll
      for (int j=0;j<4;j++)
        acc[i][j] = __builtin_amdgcn_mfma_f32_16x16x32_bf16(af[i], bfr[j], acc[i][j], 0,0,0);
    __syncthreads();
  }

  float asv[4], adv[4];
  #pragma unroll
  for (int j=0;j<4;j++) {
    int col = colBase + wc + j*16 + lm;
    float s = 0.f, d = 0.f;
    if (col < 601)      { s = asr[col];     d = adr[col]; }
    else if (col >= 640 && col - 640 < dn) { s = asn[col-640]; d = adn[col-640]; }
    asv[j] = s; adv[j] = d;
  }
  int cr = lane >> 4;
  int ct2 = blockIdx.x*2 + (wc >> 6);          // 64-col tile 0..11
  float* esp = (ct2 < 10) ? esed : esed + 2*BN_;
  #pragma unroll
  for (int i=0;i<2;i++) {
    #pragma unroll
    for (int j=0;j<4;j++) {
      int col = colBase + wc + j*16 + lm;
      #pragma unroll
      for (int g=0; g<4; g++) {
        int row = rowBase + wr + i*16 + cr*4 + g;
        C[(size_t)row*HLD_ + col] = f2b(acc[i][j][g]);
      }
    }
    #pragma unroll
    for (int g=0; g<4; g++) {
      float se = 0.f, sd = 0.f;
      #pragma unroll
      for (int j=0;j<4;j++) { se += acc[i][j][g]*asv[j]; sd += acc[i][j][g]*adv[j]; }
      #pragma unroll
      for (int o=1;o<16;o<<=1) { se += __shfl_xor(se,o,64); sd += __shfl_xor(sd,o,64); }
      if (lm == 0) {
        int row = rowBase + wr + i*16 + cr*4 + g;
        atomicAdd(&esp[row], se);
        atomicAdd(&esp[BN_ + row], sd);
      }
    }
  }
}

// ---------------- per-edge softmax weights (both heads) ----------------
// One wave per dest node; writes w_r[j], w_n[j] in csr order.

__global__ __launch_bounds__(256) void k_ew(const float* __restrict__ esed,
                                            const int* __restrict__ rowptr,
                                            const int* __restrict__ csr,
                                            float* __restrict__ wrv,
                                            float* __restrict__ wnv) {
  const float* es_r = esed;
  const float* ed_r = esed + BN_;
  const float* es_n = esed + 2*BN_;
  const float* ed_n = esed + 3*BN_;
  int wid = threadIdx.x>>6, lane = threadIdx.x&63;
  int v = blockIdx.x*4 + wid;
  int s0 = rowptr[v], e0 = rowptr[v+1];
  int deg = e0 - s0;
  if (deg == 0) return;
  float edr = ed_r[v], edn = ed_n[v];

  if (deg <= 64) {
    bool has = lane < deg;
    float er = -__builtin_inff(), en = -__builtin_inff();
    if (has) {
      int u = csr[s0 + lane];
      er = es_r[u] + edr; er = er > 0.f ? er : 0.2f*er;
      en = es_n[u] + edn; en = en > 0.f ? en : 0.2f*en;
    }
    float mr = er, mn = en;
    #pragma unroll
    for (int o=32;o;o>>=1) { mr = fmaxf(mr, __shfl_xor(mr,o,64)); mn = fmaxf(mn, __shfl_xor(mn,o,64)); }
    float pr = has ? __expf(er - mr) : 0.f;
    float pn = has ? __expf(en - mn) : 0.f;
    float dr = pr, dn2 = pn;
    #pragma unroll
    for (int o=32;o;o>>=1) { dr += __shfl_xor(dr,o,64); dn2 += __shfl_xor(dn2,o,64); }
    if (has) {
      wrv[s0 + lane] = pr * (1.f/(dr + 1e-16f));
      wnv[s0 + lane] = pn * (1.f/(dn2 + 1e-16f));
    }
  } else {
    float mr = -__builtin_inff(), mn = -__builtin_inff();
    for (int j = s0 + lane; j < e0; j += 64) {
      int u = csr[j];
      float er = es_r[u] + edr; er = er>0.f?er:0.2f*er;
      float en = es_n[u] + edn; en = en>0.f?en:0.2f*en;
      mr = fmaxf(mr, er); mn = fmaxf(mn, en);
    }
    #pragma unroll
    for (int o=32;o;o>>=1) { mr=fmaxf(mr,__shfl_xor(mr,o,64)); mn=fmaxf(mn,__shfl_xor(mn,o,64)); }
    float dr=0.f, dn2=0.f;
    for (int j = s0 + lane; j < e0; j += 64) {
      int u = csr[j];
      float er = es_r[u] + edr; er = er>0.f?er:0.2f*er;
      float en = es_n[u] + edn; en = en>0.f?en:0.2f*en;
      dr += __expf(er-mr); dn2 += __expf(en-mn);
    }
    #pragma unroll
    for (int o=32;o;o>>=1) { dr+=__shfl_xor(dr,o,64); dn2+=__shfl_xor(dn2,o,64); }
    float ir = 1.f/(dr+1e-16f), in_ = 1.f/(dn2+1e-16f);
    for (int j = s0 + lane; j < e0; j += 64) {
      int u = csr[j];
      float er = es_r[u] + edr; er = er>0.f?er:0.2f*er;
      float en = es_n[u] + edn; en = en>0.f?en:0.2f*en;
      wrv[j] = __expf(er-mr)*ir;
      wnv[j] = __expf(en-mn)*in_;
    }
  }
}

// ---------------- tiled aggregation: LDS-staged H + fused LN stats --------
// Block = (graph, 64-col chunk). Stages H[512][64cols] (64 KB LDS), then
// per node gathers from LDS with precomputed edge weights. Column sums /
// sumsq computed inline -> st (no atomics, no separate stats kernel).
// grid = 192 blocks. Chunks 0..9 use w_r, 10..11 use w_n.

__global__ __launch_bounds__(256) void k_aggt(const ushort* __restrict__ h,
                                              const float* __restrict__ wrv,
                                              const float* __restrict__ wnv,
                                              const int* __restrict__ rowptr,
                                              const int* __restrict__ csr,
                                              const float* __restrict__ bias_r,
                                              const float* __restrict__ bias_n,
                                              ushort* __restrict__ g,
                                              float* __restrict__ st,   // [2][16][768]
                                              int dn) {
  __shared__ ushort Hl[512*64];        // 64 KB
  int bid = blockIdx.x;
  int graph = bid & 15;
  int chunk = bid >> 4;                // 0..11
  int c0 = chunk * 64;
  const float* wv = (chunk < 10) ? wrv : wnv;
  int lane = threadIdx.x & 63, wid = threadIdx.x >> 6;

  // stage H slab (coalesced: 8 threads cover one row's 128 B)
  {
    int t = threadIdx.x;
    int col8 = (t & 7) * 8;
    int rb = t >> 3;                   // 0..31
    #pragma unroll
    for (int i = 0; i < 16; i++) {
      int r = i*32 + rb;
      *(short8*)&Hl[r*64 + col8] =
        *(const short8*)&h[(size_t)(graph*512 + r)*HLD_ + c0 + col8];
    }
  }
  __syncthreads();

  int col = c0 + lane;
  bool valid; float bv;
  if (col < 601)                         { bv = bias_r[col];     valid = true; }
  else if (col >= 640 && col - 640 < dn) { bv = bias_n[col-640]; valid = true; }
  else                                   { bv = 0.f;             valid = false; }

  float ssum = 0.f, sq = 0.f;
  for (int i = 0; i < 128; i++) {
    int vn = graph*512 + wid*128 + i;
    int s0 = rowptr[vn], e0 = rowptr[vn+1];
    float acc = 0.f;
    for (int base = s0; base < e0; base += 64) {
      int j = base + lane;
      float wj = 0.f; int uj = 0;
      if (j < e0) { wj = wv[j]; uj = csr[j] & 511; }
      int cl = e0 - base; if (cl > 64) cl = 64;
      // depth-2 pipelined broadcast gather
      float wb0 = __shfl(wj, 0, 64); int ub0 = __shfl(uj, 0, 64);
      ushort hv0 = Hl[ub0*64 + lane];
      for (int t = 0; t < cl; ++t) {
        float wb1 = 0.f; int ub1 = 0; ushort hv1 = 0;
        if (t+1 < cl) {
          wb1 = __shfl(wj, t+1, 64); ub1 = __shfl(uj, t+1, 64);
          hv1 = Hl[ub1*64 + lane];
        }
        acc += wb0 * b2f(hv0);
        wb0 = wb1; hv0 = hv1;
      }
    }
    float val = valid ? acc + bv : 0.f;
    g[(size_t)vn*HLD_ + col] = f2b(val);
    ssum += val; sq += val*val;
  }
  __syncthreads();                      // done with Hl contents
  float* Sf = (float*)Hl;               // reuse LDS for reduction
  Sf[wid*64 + lane]       = ssum;
  Sf[256 + wid*64 + lane] = sq;
  __syncthreads();
  if (wid == 0) {
    float s = Sf[lane] + Sf[64+lane] + Sf[128+lane] + Sf[192+lane];
    float q = Sf[256+lane] + Sf[320+lane] + Sf[384+lane] + Sf[448+lane];
    st[(size_t)graph*HLD_ + col]        = s;
    st[(size_t)(B_+graph)*HLD_ + col]   = q;
  }
}

// ---------------- LN apply + ReLU (single-partial st) ----------------

__global__ __launch_bounds__(256) void k_ln_apply(const ushort* __restrict__ g,
                                                  const float* __restrict__ st,
                                                  const float* __restrict__ scr,
                                                  const float* __restrict__ ofr,
                                                  const float* __restrict__ scn,
                                                  const float* __restrict__ ofn,
                                                  ushort* __restrict__ xb,
                                                  int dn, int Kpad) {
  int tid = threadIdx.x;
  int pp = blockIdx.x*128 + (tid & 127);
  int c0 = pp*2;
  if (c0 >= Kpad) return;
  int vbase = blockIdx.y*16;
  int b = vbase >> 9;
  float mv[2], av[2];
  #pragma unroll
  for (int q=0;q<2;q++) {
    int c = c0+q;
    int cs; bool valid; float scale, offs;
    if (c < 608) { cs = c; valid = c < 601;
                   scale = valid ? scr[c] : 0.f; offs = valid ? ofr[c] : 0.f; }
    else { int cn = c - 608; cs = 640 + cn; valid = cn < dn;
           scale = valid ? scn[cn] : 0.f; offs = valid ? ofn[cn] : 0.f; }
    float mul = 0.f, add = 0.f;
    if (valid) {
      float s  = st[(size_t)b*HLD_ + cs];
      float qq = st[(size_t)(B_+b)*HLD_ + cs];
      float mu = s*(1.f/N_);
      float var = qq*(1.f/N_) - mu*mu;
      float rs = rsqrtf(var+1e-5f);
      mul = rs*scale;
      add = offs - mu*rs*scale;
    }
    mv[q] = mul; av[q] = add;
  }
  int cs0 = (c0 < 608) ? c0 : 640 + (c0 - 608);
  for (int i = tid >> 7; i < 16; i += 2) {
    int v = vbase + i;
    uint gg = *(const uint*)&g[(size_t)v*HLD_ + cs0];
    float x0 = b2f((ushort)(gg & 0xFFFFu));
    float x1 = b2f((ushort)(gg >> 16));
    float y0 = x0*mv[0] + av[0]; y0 = y0 > 0.f ? y0 : 0.f;
    float y1 = x1*mv[1] + av[1]; y1 = y1 > 0.f ? y1 : 0.f;
    *(uint*)&xb[(size_t)v*Kpad + c0] = ((uint)f2b(y1) << 16) | f2b(y0);
  }
}

// ---------------- final: reward = L4 st sums; ns_new assembly -------------

__global__ __launch_bounds__(256) void k_final(const float* __restrict__ st,
                                               const ushort* __restrict__ g,
                                               const float* __restrict__ ns,
                                               float* __restrict__ out) {
  int idx = blockIdx.x*256+threadIdx.x;
  if (idx < OUT_R_) {
    int b = idx / FSS_, c = idx - b*FSS_;
    out[idx] = st[(size_t)b*HLD_ + c];
  } else {
    int j2 = idx - OUT_R_;
    if (j2 >= B_*NSROW_) return;
    int b = j2 / NSROW_; int j = j2 - b*NSROW_;
    float v;
    if (j < SLEFT_) {
      int n = j >> 5, c = j & 31;
      v = b2f(g[(size_t)(b*N_+n)*HLD_ + 640 + c]);
    } else {
      v = ns[(size_t)b*NSROW_ + j];
    }
    out[idx] = v;
  }
}

// ---------------- host driver ----------------

extern "C" void kernel_launch(void* const* d_in, const int* in_sizes, int n_in,
                              void* d_out, int out_size, void* d_ws, size_t ws_size,
                              hipStream_t stream) {
  const float* ns = (const float*)d_in[0];
  const int*   a  = (const int*)d_in[1];

  const float *W[4], *As[4], *Ad[4], *Bb[4], *Sc[3], *Of[3];
  const float *rW[4], *rAs[4], *rAd[4], *rBb[4], *rSc[3], *rOf[3];
  int p = 2;
  for (int i=0;i<4;i++){
    W[i]=(const float*)d_in[p++]; As[i]=(const float*)d_in[p++];
    Ad[i]=(const float*)d_in[p++]; Bb[i]=(const float*)d_in[p++];
    if (i<3){ Sc[i]=(const float*)d_in[p++]; Of[i]=(const float*)d_in[p++]; }
  }
  for (int i=0;i<4;i++){
    rW[i]=(const float*)d_in[p++]; rAs[i]=(const float*)d_in[p++];
    rAd[i]=(const float*)d_in[p++]; rBb[i]=(const float*)d_in[p++];
    if (i<3){ rSc[i]=(const float*)d_in[p++]; rOf[i]=(const float*)d_in[p++]; }
  }

  char* w = (char*)d_ws;
  auto carve = [&](size_t bytes)->void* {
    void* r = (void*)w;
    w += (bytes + 255) & ~(size_t)255;
    return r;
  };
  ushort* xb   = (ushort*)carve((size_t)BN_*736*2);
  ushort* hbuf = (ushort*)carve((size_t)BN_*HLD_*2);
  ushort* gbuf = (ushort*)carve((size_t)BN_*HLD_*2);
  ushort* sabf = (ushort*)carve((size_t)BN_*64*2);
  float* esed  = (float*)carve((size_t)4*BN_*4);    // es_r|ed_r|es_n|ed_n
  float* wrv   = (float*)carve((size_t)BE_*4);
  float* wnv   = (float*)carve((size_t)BE_*4);
  float* st    = (float*)carve((size_t)2*B_*HLD_*4);
  int* src_i   = (int*)carve((size_t)BE_*4);
  int* dst_i   = (int*)carve((size_t)BE_*4);
  int* cnt     = (int*)carve((size_t)2*BN_*4);      // cnt | fill
  int* fill    = cnt + BN_;
  int* rowptr  = (int*)carve((size_t)(BN_+1)*4);
  int* csr_src = (int*)carve((size_t)BE_*4);
  ushort* Wt[4];
  Wt[0] = (ushort*)carve((size_t)768*64*2);
  Wt[1] = (ushort*)carve((size_t)768*736*2);
  Wt[2] = (ushort*)carve((size_t)768*672*2);
  Wt[3] = (ushort*)carve((size_t)768*672*2);

  float* out = (float*)d_out;

  hipMemsetAsync(cnt, 0, (size_t)2*BN_*4, stream);

  k_indices<<<(BE_+255)/256, 256, 0, stream>>>(ns, src_i, dst_i, cnt);
  k_scan<<<1, 1024, 0, stream>>>(cnt, rowptr);
  k_scatter<<<(BE_+255)/256, 256, 0, stream>>>(src_i, dst_i, rowptr, fill, csr_src);
  k_sa<<<(BN_*64+255)/256, 256, 0, stream>>>(ns, a, sabf);

  WtP wtp;
  for (int i=0;i<4;i++){ wtp.Wr[i]=rW[i]; wtp.Wn[i]=W[i]; wtp.T[i]=Wt[i]; }
  k_wt_tr<<<1608, 256, 0, stream>>>(wtp);

  dim3 ggrid(6, BN_/64);   // 768 blocks

  const ushort* xin[4] = { sabf, xb, xb, xb };
  int Kp[4]  = { 64, 736, 672, 672 };
  int dns[4] = { 128, 64, 64, 32 };

  for (int L=0; L<4; ++L) {
    hipMemsetAsync(esed, 0, (size_t)4*BN_*4, stream);
    k_gemm<<<ggrid, 256, 0, stream>>>(xin[L], Wt[L], hbuf, esed,
                                      rAs[L], rAd[L], As[L], Ad[L], Kp[L], dns[L]);
    k_ew<<<BN_/4, 256, 0, stream>>>(esed, rowptr, csr_src, wrv, wnv);
    k_aggt<<<192, 256, 0, stream>>>(hbuf, wrv, wnv, rowptr, csr_src,
                                    rBb[L], Bb[L], gbuf, st, dns[L]);
    if (L < 3) {
      int Kpn = (L==0) ? 736 : 672;
      k_ln_apply<<<dim3(3, BN_/16), 256, 0, stream>>>(gbuf, st,
                  rSc[L], rOf[L], Sc[L], Of[L], xb, dns[L], Kpn);
    }
  }

  k_final<<<(OUT_R_ + B_*NSROW_ + 255)/256, 256, 0, stream>>>(st, gbuf, ns, out);
}

// Round 13
// 397.107 us; speedup vs baseline: 3.5265x; 3.5265x over previous
//
#include <hip/hip_runtime.h>
#include <math.h>

#define B_ 16
#define N_ 512
#define D_ 32
#define E_ 8176
#define SLEFT_ 16384
#define FSS_ 601
#define BN_ (B_*N_)            // 8192
#define BE_ (B_*E_)            // 130816
#define NSROW_ (SLEFT_ + 2*E_) // 32736
#define OUT_R_ (B_*FSS_)       // 9616
#define HLD_ 768               // combined width: reward 0..639, next 640..767

typedef __attribute__((ext_vector_type(8))) short short8;
typedef __attribute__((ext_vector_type(4))) float f32x4;

typedef __attribute__((address_space(3))) uint lds_uint;
typedef __attribute__((address_space(1))) const uint g_uint;

__device__ __forceinline__ void gl_lds16(const ushort* gp, ushort* lp) {
  __builtin_amdgcn_global_load_lds((g_uint*)gp, (lds_uint*)lp, 16, 0, 0);
}

__device__ __forceinline__ ushort f2b(float f) {
  uint u = __builtin_bit_cast(uint, f);
  u += 0x7FFFu + ((u >> 16) & 1u);
  return (ushort)(u >> 16);
}
__device__ __forceinline__ float b2f(ushort h) {
  return __builtin_bit_cast(float, ((uint)h) << 16);
}

// ---------------- index / CSR build ----------------

__global__ __launch_bounds__(256) void k_indices(const float* __restrict__ ns,
                                                 int* __restrict__ src_i,
                                                 int* __restrict__ dst_i,
                                                 int* __restrict__ cnt) {
  int idx = blockIdx.x*256 + threadIdx.x;
  if (idx >= BE_) return;
  int b = idx / E_;
  int j = idx - b*E_;
  const float* row = ns + (size_t)b*NSROW_;
  int s = (int)row[SLEFT_ + j];
  int r = (int)row[SLEFT_ + E_ + j];
  src_i[idx] = b*N_ + s;
  int dst = b*N_ + r;
  dst_i[idx] = dst;
  atomicAdd(&cnt[dst], 1);
}

__global__ __launch_bounds__(1024) void k_scan(const int* __restrict__ cnt,
                                               int* __restrict__ rowptr) {
  __shared__ int part[1024];
  int t = threadIdx.x;
  int base = t*8;
  int loc[8]; int s = 0;
  #pragma unroll
  for (int i=0;i<8;i++){ loc[i]=cnt[base+i]; s+=loc[i]; }
  part[t]=s; __syncthreads();
  for (int off=1; off<1024; off<<=1) {
    int v = (t>=off)?part[t-off]:0;
    __syncthreads();
    part[t]+=v;
    __syncthreads();
  }
  int ex = (t==0)?0:part[t-1];
  #pragma unroll
  for (int i=0;i<8;i++){ rowptr[base+i]=ex; ex+=loc[i]; }
  if (t==1023) rowptr[BN_]=ex;
}

__global__ __launch_bounds__(256) void k_scatter(const int* __restrict__ src_i,
                                                 const int* __restrict__ dst_i,
                                                 const int* __restrict__ rowptr,
                                                 int* __restrict__ fill,
                                                 int* __restrict__ csr_src) {
  int idx = blockIdx.x*256+threadIdx.x;
  if (idx>=BE_) return;
  int dst = dst_i[idx];
  int pos = rowptr[dst] + atomicAdd(&fill[dst],1);
  csr_src[pos] = src_i[idx];
}

// ---------------- sa (bf16, padded to K=64) ----------------

__global__ __launch_bounds__(256) void k_sa(const float* __restrict__ ns,
                                            const int* __restrict__ a,
                                            ushort* __restrict__ sa) {
  int idx = blockIdx.x*256+threadIdx.x;
  if (idx >= BN_*64) return;
  int v = idx >> 6, c = idx & 63;
  int b = v >> 9, n = v & 511;
  float val = 0.f;
  if (c < 32)       val = ns[(size_t)b*NSROW_ + n*32 + c];
  else if (c == 32) val = (a[b]==n) ? 1.f : 0.f;
  sa[idx] = f2b(val);
}

// ---------------- LDS-tiled block-diagonal weight transpose ---------------

struct WtP { const float* Wr[4]; const float* Wn[4]; ushort* T[4]; };

__global__ __launch_bounds__(256) void k_wt_tr(WtP p) {
  int t = blockIdx.x;
  int s, base, KP, DINR, DINN, DOUTN, KOFF;
  if (t < 48)        { s=0; base=0;    KP=64;  DINR=33;  DINN=33;  DOUTN=128; KOFF=0;   }
  else if (t < 600)  { s=1; base=48;   KP=736; DINR=601; DINN=128; DOUTN=64;  KOFF=608; }
  else if (t < 1104) { s=2; base=600;  KP=672; DINR=601; DINN=64;  DOUTN=64;  KOFF=608; }
  else               { s=3; base=1104; KP=672; DINR=601; DINN=64;  DOUTN=32;  KOFF=608; }
  int ti = t - base;
  int kt = ti / 24, nt = ti - kt*24;
  int k0 = kt*32, n0 = nt*32;
  __shared__ float tile[32][33];
  int tid = threadIdx.x;
  int cc = tid & 31, rr = tid >> 5;
  #pragma unroll
  for (int it=0; it<4; it++) {
    int k = k0 + it*8 + rr;
    int n = n0 + cc;
    float v = 0.f;
    if (n < 640) { if (n < 601 && k < DINR) v = p.Wr[s][(size_t)k*601 + n]; }
    else { int nn = n-640, kk = k-KOFF;
           if (nn < DOUTN && kk >= 0 && kk < DINN) v = p.Wn[s][(size_t)kk*DOUTN + nn]; }
    tile[it*8+rr][cc] = v;
  }
  __syncthreads();
  #pragma unroll
  for (int it=0; it<4; it++) {
    int n = n0 + it*8 + rr;
    int k = k0 + cc;
    p.T[s][(size_t)n*KP + k] = f2b(tile[cc][it*8+rr]);
  }
}

// ---------------- MFMA bf16 GEMM, 64x128 tile + atomic final es/ed --------
// 64-col tiles 0..9 -> reward accumulators, 10..11 -> next head.

__global__ __launch_bounds__(256) void k_gemm(const ushort* __restrict__ A,
                                              const ushort* __restrict__ Bt,
                                              ushort* __restrict__ C,
                                              float* __restrict__ esed, // es_r|ed_r|es_n|ed_n
                                              const float* __restrict__ asr,
                                              const float* __restrict__ adr,
                                              const float* __restrict__ asn,
                                              const float* __restrict__ adn,
                                              int Kpad, int dn) {
  __shared__ ushort Asm[64*32];
  __shared__ ushort Bsm[128*32];
  int tid = threadIdx.x;
  int rowBase = blockIdx.y * 64;
  int colBase = blockIdx.x * 128;
  int wave = tid >> 6, lane = tid & 63;
  int wr = (wave >> 1) * 32, wc = (wave & 1) * 64;
  int lm = lane & 15, lk = (lane >> 4) * 8;

  f32x4 acc[2][4];
  #pragma unroll
  for (int i=0;i<2;i++)
    #pragma unroll
    for (int j=0;j<4;j++) acc[i][j] = (f32x4){0.f,0.f,0.f,0.f};

  int t0 = tid, t1 = tid + 256;
  const ushort* Ag0 = A  + (size_t)(rowBase + (t0>>2))*Kpad + (t0&3)*8;
  const ushort* Bg0 = Bt + (size_t)(colBase + (t0>>2))*Kpad + (t0&3)*8;
  const ushort* Bg1 = Bt + (size_t)(colBase + (t1>>2))*Kpad + (t1&3)*8;
  ushort* Al0 = &Asm[t0*8];
  ushort* Bl0 = &Bsm[t0*8];
  ushort* Bl1 = &Bsm[t1*8];

  for (int k0 = 0; k0 < Kpad; k0 += 32) {
    gl_lds16(Ag0 + k0, Al0);
    gl_lds16(Bg0 + k0, Bl0);
    gl_lds16(Bg1 + k0, Bl1);
    __syncthreads();
    short8 af[2], bfr[4];
    #pragma unroll
    for (int i=0;i<2;i++) af[i]  = *(short8*)&Asm[(wr + i*16 + lm)*32 + lk];
    #pragma unroll
    for (int j=0;j<4;j++) bfr[j] = *(short8*)&Bsm[(wc + j*16 + lm)*32 + lk];
    #pragma unroll
    for (int i=0;i<2;i++)
      #pragma unroll
      for (int j=0;j<4;j++)
        acc[i][j] = __builtin_amdgcn_mfma_f32_16x16x32_bf16(af[i], bfr[j], acc[i][j], 0,0,0);
    __syncthreads();
  }

  float asv[4], adv[4];
  #pragma unroll
  for (int j=0;j<4;j++) {
    int col = colBase + wc + j*16 + lm;
    float s = 0.f, d = 0.f;
    if (col < 601)      { s = asr[col];     d = adr[col]; }
    else if (col >= 640 && col - 640 < dn) { s = asn[col-640]; d = adn[col-640]; }
    asv[j] = s; adv[j] = d;
  }
  int cr = lane >> 4;
  int ct2 = blockIdx.x*2 + (wc >> 6);          // 64-col tile 0..11
  float* esp = (ct2 < 10) ? esed : esed + 2*BN_;
  #pragma unroll
  for (int i=0;i<2;i++) {
    #pragma unroll
    for (int j=0;j<4;j++) {
      int col = colBase + wc + j*16 + lm;
      #pragma unroll
      for (int g=0; g<4; g++) {
        int row = rowBase + wr + i*16 + cr*4 + g;
        C[(size_t)row*HLD_ + col] = f2b(acc[i][j][g]);
      }
    }
    #pragma unroll
    for (int g=0; g<4; g++) {
      float se = 0.f, sd = 0.f;
      #pragma unroll
      for (int j=0;j<4;j++) { se += acc[i][j][g]*asv[j]; sd += acc[i][j][g]*adv[j]; }
      #pragma unroll
      for (int o=1;o<16;o<<=1) { se += __shfl_xor(se,o,64); sd += __shfl_xor(sd,o,64); }
      if (lm == 0) {
        int row = rowBase + wr + i*16 + cr*4 + g;
        atomicAdd(&esp[row], se);
        atomicAdd(&esp[BN_ + row], sd);
      }
    }
  }
}

// ---------------- combined softmax + aggregation (one wave per node) ------
// Scalar es/ed per head (from gemm atomics). 4-wide unrolled gather: up to
// 8 independent 16B loads in flight per lane before the FMA block.

__global__ __launch_bounds__(256) void k_agg(const ushort* __restrict__ h,
                                             const float* __restrict__ esed,
                                             const int* __restrict__ rowptr,
                                             const int* __restrict__ csr,
                                             const float* __restrict__ bias_r,
                                             const float* __restrict__ bias_n,
                                             ushort* __restrict__ g,
                                             int dn) {
  const float* es_r = esed;
  const float* ed_r = esed + BN_;
  const float* es_n = esed + 2*BN_;
  const float* ed_n = esed + 3*BN_;
  int wid = threadIdx.x>>6, lane = threadIdx.x&63;
  int bid = blockIdx.x;
  int xcd = bid & 7, slot = bid >> 3;
  int graph = xcd + ((slot >> 7) << 3);
  int v = graph*512 + (slot & 127)*4 + wid;
  int s0 = rowptr[v], e0 = rowptr[v+1];
  int deg = e0 - s0;
  float edr = ed_r[v], edn = ed_n[v];

  int ch0 = lane, ch1 = lane + 64;
  bool a1 = ch1 < 96;
  bool c1r = ch1 < 80;
  float acc0[8], acc1[8];
  #pragma unroll
  for (int q=0;q<8;q++){ acc0[q]=0.f; acc1[q]=0.f; }

  if (deg <= 64) {
    bool has = lane < deg;
    int u = 0; float er = -__builtin_inff(), en = -__builtin_inff();
    if (has) {
      u = csr[s0 + lane];
      er = es_r[u] + edr; er = er > 0.f ? er : 0.2f*er;
      en = es_n[u] + edn; en = en > 0.f ? en : 0.2f*en;
    }
    float mr = er, mn = en;
    #pragma unroll
    for (int o=32;o;o>>=1) { mr = fmaxf(mr, __shfl_xor(mr,o,64)); mn = fmaxf(mn, __shfl_xor(mn,o,64)); }
    float pr = has ? __expf(er - mr) : 0.f;
    float pn = has ? __expf(en - mn) : 0.f;
    float dr = pr, dnm = pn;
    #pragma unroll
    for (int o=32;o;o>>=1) { dr += __shfl_xor(dr,o,64); dnm += __shfl_xor(dnm,o,64); }
    pr *= 1.f/(dr + 1e-16f);
    pn *= 1.f/(dnm + 1e-16f);

    for (int t0 = 0; t0 < deg; t0 += 4) {
      int nt = deg - t0; if (nt > 4) nt = 4;
      short8 va[4], vb[4];
      float w0[4], w1[4];
      #pragma unroll
      for (int q=0;q<4;q++) {
        if (q < nt) {
          int uu = __shfl(u, t0+q, 64);
          w0[q] = __shfl(pr, t0+q, 64);
          w1[q] = __shfl(pn, t0+q, 64);
          const ushort* hp = h + (size_t)uu*HLD_;
          va[q] = *(const short8*)&hp[ch0*8];
          vb[q] = a1 ? *(const short8*)&hp[ch1*8] : short8{};
        } else {
          w0[q] = 0.f; w1[q] = 0.f; va[q] = short8{}; vb[q] = short8{};
        }
      }
      #pragma unroll
      for (int q=0;q<4;q++) {
        #pragma unroll
        for (int r=0;r<8;r++) acc0[r] += w0[q] * b2f((ushort)va[q][r]);
        if (a1) {
          float wv = c1r ? w0[q] : w1[q];
          #pragma unroll
          for (int r=0;r<8;r++) acc1[r] += wv * b2f((ushort)vb[q][r]);
        }
      }
    }
  } else {
    // slow path (deg > 64)
    float mr = -__builtin_inff(), mn = -__builtin_inff();
    for (int j = s0 + lane; j < e0; j += 64) {
      int u = csr[j];
      float er = es_r[u] + edr; er = er>0.f?er:0.2f*er;
      float en = es_n[u] + edn; en = en>0.f?en:0.2f*en;
      mr = fmaxf(mr, er); mn = fmaxf(mn, en);
    }
    #pragma unroll
    for (int o=32;o;o>>=1) { mr=fmaxf(mr,__shfl_xor(mr,o,64)); mn=fmaxf(mn,__shfl_xor(mn,o,64)); }
    float dr=0.f, dnm=0.f;
    for (int j = s0 + lane; j < e0; j += 64) {
      int u = csr[j];
      float er = es_r[u] + edr; er = er>0.f?er:0.2f*er;
      float en = es_n[u] + edn; en = en>0.f?en:0.2f*en;
      dr += __expf(er-mr); dnm += __expf(en-mn);
    }
    #pragma unroll
    for (int o=32;o;o>>=1) { dr+=__shfl_xor(dr,o,64); dnm+=__shfl_xor(dnm,o,64); }
    float ir = 1.f/(dr+1e-16f), in_ = 1.f/(dnm+1e-16f);
    for (int j = s0; j < e0; ++j) {
      int uu = csr[j];
      float er = es_r[uu] + edr; er = er>0.f?er:0.2f*er;
      float en = es_n[uu] + edn; en = en>0.f?en:0.2f*en;
      float wr2 = __expf(er-mr)*ir, wn2 = __expf(en-mn)*in_;
      const ushort* hp = h + (size_t)uu*HLD_;
      short8 hv = *(const short8*)&hp[ch0*8];
      #pragma unroll
      for (int q=0;q<8;q++) acc0[q] += wr2 * b2f((ushort)hv[q]);
      if (a1) {
        short8 hv2 = *(const short8*)&hp[ch1*8];
        float wv = c1r ? wr2 : wn2;
        #pragma unroll
        for (int q=0;q<8;q++) acc1[q] += wv * b2f((ushort)hv2[q]);
      }
    }
  }

  ushort* gv = g + (size_t)v*HLD_;
  {
    int cb = ch0*8;
    short8 ov;
    #pragma unroll
    for (int q=0;q<8;q++) ov[q] = (short)f2b(acc0[q] + bias_r[cb+q]);
    *(short8*)&gv[cb] = ov;
  }
  if (a1) {
    int cb = ch1*8;
    short8 ov;
    #pragma unroll
    for (int q=0;q<8;q++) {
      int c = cb+q;
      float val;
      if (c < 601)                         val = acc1[q] + bias_r[c];
      else if (c >= 640 && (c-640) < dn)   val = acc1[q] + bias_n[c-640];
      else                                 val = 0.f;
      ov[q] = (short)f2b(val);
    }
    *(short8*)&gv[cb] = ov;
  }
}

// ---------------- LN stats partials over all 768 cols ----------------

__global__ __launch_bounds__(256) void k_ln_stats(const ushort* __restrict__ g,
                                                  float* __restrict__ st) {
  int b = blockIdx.y, z = blockIdx.z; int n0 = z*64;
  int lc = threadIdx.x & 63, r0 = threadIdx.x >> 6;
  int c = blockIdx.x*64 + lc;
  float s=0.f, q=0.f;
  #pragma unroll 4
  for (int i=0;i<16;i++) {
    int n = n0 + r0*16 + i;
    float x = b2f(g[(size_t)(b*N_+n)*HLD_ + c]);
    s+=x; q+=x*x;
  }
  __shared__ float S[4][64], Q[4][64];
  S[r0][lc]=s; Q[r0][lc]=q; __syncthreads();
  if (r0==0) {
    st[((size_t)(z*2+0)*B_ + b)*HLD_ + c] = S[0][lc]+S[1][lc]+S[2][lc]+S[3][lc];
    st[((size_t)(z*2+1)*B_ + b)*HLD_ + c] = Q[0][lc]+Q[1][lc]+Q[2][lc]+Q[3][lc];
  }
}

// ---------------- LN apply + ReLU (finalize folded; col pair x 16 rows) ---

__global__ __launch_bounds__(256) void k_ln_apply(const ushort* __restrict__ g,
                                                  const float* __restrict__ st,
                                                  const float* __restrict__ scr,
                                                  const float* __restrict__ ofr,
                                                  const float* __restrict__ scn,
                                                  const float* __restrict__ ofn,
                                                  ushort* __restrict__ xb,
                                                  int dn, int Kpad) {
  int tid = threadIdx.x;
  int pp = blockIdx.x*128 + (tid & 127);
  int c0 = pp*2;
  if (c0 >= Kpad) return;
  int vbase = blockIdx.y*16;
  int b = vbase >> 9;
  float mv[2], av[2];
  #pragma unroll
  for (int q=0;q<2;q++) {
    int c = c0+q;
    int cs; bool valid; float scale, offs;
    if (c < 608) { cs = c; valid = c < 601;
                   scale = valid ? scr[c] : 0.f; offs = valid ? ofr[c] : 0.f; }
    else { int cn = c - 608; cs = 640 + cn; valid = cn < dn;
           scale = valid ? scn[cn] : 0.f; offs = valid ? ofn[cn] : 0.f; }
    float mul = 0.f, add = 0.f;
    if (valid) {
      float s=0.f, qq=0.f;
      #pragma unroll
      for (int z=0;z<8;z++) {
        s  += st[((size_t)(z*2+0)*B_ + b)*HLD_ + cs];
        qq += st[((size_t)(z*2+1)*B_ + b)*HLD_ + cs];
      }
      float mu = s*(1.f/N_);
      float var = qq*(1.f/N_) - mu*mu;
      float rs = rsqrtf(var+1e-5f);
      mul = rs*scale;
      add = offs - mu*rs*scale;
    }
    mv[q] = mul; av[q] = add;
  }
  int cs0 = (c0 < 608) ? c0 : 640 + (c0 - 608);
  for (int i = tid >> 7; i < 16; i += 2) {
    int v = vbase + i;
    uint gg = *(const uint*)&g[(size_t)v*HLD_ + cs0];
    float x0 = b2f((ushort)(gg & 0xFFFFu));
    float x1 = b2f((ushort)(gg >> 16));
    float y0 = x0*mv[0] + av[0]; y0 = y0 > 0.f ? y0 : 0.f;
    float y1 = x1*mv[1] + av[1]; y1 = y1 > 0.f ? y1 : 0.f;
    *(uint*)&xb[(size_t)v*Kpad + c0] = ((uint)f2b(y1) << 16) | f2b(y0);
  }
}

// ---------------- reward: sum over nodes (slot partials) ----------------

__global__ __launch_bounds__(256) void k_rsum(const ushort* __restrict__ g,
                                              float* __restrict__ rsp) {
  int b = blockIdx.y, z = blockIdx.z; int n0 = z*64;
  int lc = threadIdx.x & 63, r0 = threadIdx.x>>6;
  int c = blockIdx.x*64 + lc;
  float s = 0.f;
  if (c < FSS_) {
    #pragma unroll 4
    for (int i=0;i<16;i++) {
      int n = n0 + r0*16 + i;
      s += b2f(g[(size_t)(b*N_+n)*HLD_ + c]);
    }
  }
  __shared__ float S[4][64];
  S[r0][lc]=s; __syncthreads();
  if (r0==0 && c<FSS_)
    rsp[((size_t)z*B_ + b)*FSS_ + c] = S[0][lc]+S[1][lc]+S[2][lc]+S[3][lc];
}

// ---------------- final: reward finalize + ns_new assembly ----------------

__global__ __launch_bounds__(256) void k_final(const float* __restrict__ rsp,
                                               const ushort* __restrict__ g,
                                               const float* __restrict__ ns,
                                               float* __restrict__ out) {
  int idx = blockIdx.x*256+threadIdx.x;
  if (idx < OUT_R_) {
    int b = idx / FSS_, c = idx - b*FSS_;
    float s = 0.f;
    #pragma unroll
    for (int z=0;z<8;z++) s += rsp[((size_t)z*B_ + b)*FSS_ + c];
    out[idx] = s;
  } else {
    int j2 = idx - OUT_R_;
    if (j2 >= B_*NSROW_) return;
    int b = j2 / NSROW_; int j = j2 - b*NSROW_;
    float v;
    if (j < SLEFT_) {
      int n = j >> 5, c = j & 31;
      v = b2f(g[(size_t)(b*N_+n)*HLD_ + 640 + c]);
    } else {
      v = ns[(size_t)b*NSROW_ + j];
    }
    out[idx] = v;
  }
}

// ---------------- host driver ----------------

extern "C" void kernel_launch(void* const* d_in, const int* in_sizes, int n_in,
                              void* d_out, int out_size, void* d_ws, size_t ws_size,
                              hipStream_t stream) {
  const float* ns = (const float*)d_in[0];
  const int*   a  = (const int*)d_in[1];

  const float *W[4], *As[4], *Ad[4], *Bb[4], *Sc[3], *Of[3];
  const float *rW[4], *rAs[4], *rAd[4], *rBb[4], *rSc[3], *rOf[3];
  int p = 2;
  for (int i=0;i<4;i++){
    W[i]=(const float*)d_in[p++]; As[i]=(const float*)d_in[p++];
    Ad[i]=(const float*)d_in[p++]; Bb[i]=(const float*)d_in[p++];
    if (i<3){ Sc[i]=(const float*)d_in[p++]; Of[i]=(const float*)d_in[p++]; }
  }
  for (int i=0;i<4;i++){
    rW[i]=(const float*)d_in[p++]; rAs[i]=(const float*)d_in[p++];
    rAd[i]=(const float*)d_in[p++]; rBb[i]=(const float*)d_in[p++];
    if (i<3){ rSc[i]=(const float*)d_in[p++]; rOf[i]=(const float*)d_in[p++]; }
  }

  char* w = (char*)d_ws;
  auto carve = [&](size_t bytes)->void* {
    void* r = (void*)w;
    w += (bytes + 255) & ~(size_t)255;
    return r;
  };
  ushort* xb   = (ushort*)carve((size_t)BN_*736*2);
  ushort* hbuf = (ushort*)carve((size_t)BN_*HLD_*2);
  ushort* gbuf = (ushort*)carve((size_t)BN_*HLD_*2);
  ushort* sabf = (ushort*)carve((size_t)BN_*64*2);
  float* esed  = (float*)carve((size_t)4*BN_*4);    // es_r|ed_r|es_n|ed_n
  float* stp   = (float*)carve((size_t)16*B_*HLD_*4);
  float* rsp   = (float*)carve((size_t)8*B_*FSS_*4);
  int* src_i   = (int*)carve((size_t)BE_*4);
  int* dst_i   = (int*)carve((size_t)BE_*4);
  int* cnt     = (int*)carve((size_t)2*BN_*4);      // cnt | fill
  int* fill    = cnt + BN_;
  int* rowptr  = (int*)carve((size_t)(BN_+1)*4);
  int* csr_src = (int*)carve((size_t)BE_*4);
  ushort* Wt[4];
  Wt[0] = (ushort*)carve((size_t)768*64*2);
  Wt[1] = (ushort*)carve((size_t)768*736*2);
  Wt[2] = (ushort*)carve((size_t)768*672*2);
  Wt[3] = (ushort*)carve((size_t)768*672*2);

  float* out = (float*)d_out;

  hipMemsetAsync(cnt, 0, (size_t)2*BN_*4, stream);

  k_indices<<<(BE_+255)/256, 256, 0, stream>>>(ns, src_i, dst_i, cnt);
  k_scan<<<1, 1024, 0, stream>>>(cnt, rowptr);
  k_scatter<<<(BE_+255)/256, 256, 0, stream>>>(src_i, dst_i, rowptr, fill, csr_src);
  k_sa<<<(BN_*64+255)/256, 256, 0, stream>>>(ns, a, sabf);

  WtP wtp;
  for (int i=0;i<4;i++){ wtp.Wr[i]=rW[i]; wtp.Wn[i]=W[i]; wtp.T[i]=Wt[i]; }
  k_wt_tr<<<1608, 256, 0, stream>>>(wtp);

  dim3 ggrid(6, BN_/64);   // 768 blocks

  const ushort* xin[4] = { sabf, xb, xb, xb };
  int Kp[4]  = { 64, 736, 672, 672 };
  int dns[4] = { 128, 64, 64, 32 };

  for (int L=0; L<4; ++L) {
    hipMemsetAsync(esed, 0, (size_t)4*BN_*4, stream);
    k_gemm<<<ggrid, 256, 0, stream>>>(xin[L], Wt[L], hbuf, esed,
                                      rAs[L], rAd[L], As[L], Ad[L], Kp[L], dns[L]);
    k_agg<<<BN_/4, 256, 0, stream>>>(hbuf, esed, rowptr, csr_src,
                                     rBb[L], Bb[L], gbuf, dns[L]);
    if (L < 3) {
      k_ln_stats<<<dim3(12, B_, 8), 256, 0, stream>>>(gbuf, stp);
      int Kpn = (L==0) ? 736 : 672;
      k_ln_apply<<<dim3(3, BN_/16), 256, 0, stream>>>(gbuf, stp,
                  rSc[L], rOf[L], Sc[L], Of[L], xb, dns[L], Kpn);
    }
  }

  k_rsum<<<dim3(10, B_, 8), 256, 0, stream>>>(gbuf, rsp);
  k_final<<<(OUT_R_ + B_*NSROW_ + 255)/256, 256, 0, stream>>>(rsp, gbuf, ns, out);
}

// Round 14
// 384.558 us; speedup vs baseline: 3.6416x; 1.0326x over previous
//
#include <hip/hip_runtime.h>
#include <math.h>

#define B_ 16
#define N_ 512
#define D_ 32
#define E_ 8176
#define SLEFT_ 16384
#define FSS_ 601
#define BN_ (B_*N_)            // 8192
#define BE_ (B_*E_)            // 130816
#define NSROW_ (SLEFT_ + 2*E_) // 32736
#define OUT_R_ (B_*FSS_)       // 9616
#define HLD_ 768               // combined width: reward 0..639, next 640..767

typedef __attribute__((ext_vector_type(8))) short short8;
typedef __attribute__((ext_vector_type(4))) float f32x4;

typedef __attribute__((address_space(3))) uint lds_uint;
typedef __attribute__((address_space(1))) const uint g_uint;

__device__ __forceinline__ void gl_lds16(const ushort* gp, ushort* lp) {
  __builtin_amdgcn_global_load_lds((g_uint*)gp, (lds_uint*)lp, 16, 0, 0);
}

__device__ __forceinline__ ushort f2b(float f) {
  uint u = __builtin_bit_cast(uint, f);
  u += 0x7FFFu + ((u >> 16) & 1u);
  return (ushort)(u >> 16);
}
__device__ __forceinline__ float b2f(ushort h) {
  return __builtin_bit_cast(float, ((uint)h) << 16);
}

// ---------------- index / CSR build ----------------

__global__ __launch_bounds__(256) void k_indices(const float* __restrict__ ns,
                                                 int* __restrict__ src_i,
                                                 int* __restrict__ dst_i,
                                                 int* __restrict__ cnt) {
  int idx = blockIdx.x*256 + threadIdx.x;
  if (idx >= BE_) return;
  int b = idx / E_;
  int j = idx - b*E_;
  const float* row = ns + (size_t)b*NSROW_;
  int s = (int)row[SLEFT_ + j];
  int r = (int)row[SLEFT_ + E_ + j];
  src_i[idx] = b*N_ + s;
  int dst = b*N_ + r;
  dst_i[idx] = dst;
  atomicAdd(&cnt[dst], 1);
}

__global__ __launch_bounds__(1024) void k_scan(const int* __restrict__ cnt,
                                               int* __restrict__ rowptr) {
  __shared__ int part[1024];
  int t = threadIdx.x;
  int base = t*8;
  int loc[8]; int s = 0;
  #pragma unroll
  for (int i=0;i<8;i++){ loc[i]=cnt[base+i]; s+=loc[i]; }
  part[t]=s; __syncthreads();
  for (int off=1; off<1024; off<<=1) {
    int v = (t>=off)?part[t-off]:0;
    __syncthreads();
    part[t]+=v;
    __syncthreads();
  }
  int ex = (t==0)?0:part[t-1];
  #pragma unroll
  for (int i=0;i<8;i++){ rowptr[base+i]=ex; ex+=loc[i]; }
  if (t==1023) rowptr[BN_]=ex;
}

__global__ __launch_bounds__(256) void k_scatter(const int* __restrict__ src_i,
                                                 const int* __restrict__ dst_i,
                                                 const int* __restrict__ rowptr,
                                                 int* __restrict__ fill,
                                                 int* __restrict__ csr_src) {
  int idx = blockIdx.x*256+threadIdx.x;
  if (idx>=BE_) return;
  int dst = dst_i[idx];
  int pos = rowptr[dst] + atomicAdd(&fill[dst],1);
  csr_src[pos] = src_i[idx];
}

// ---------------- sa (bf16, padded to K=64) ----------------

__global__ __launch_bounds__(256) void k_sa(const float* __restrict__ ns,
                                            const int* __restrict__ a,
                                            ushort* __restrict__ sa) {
  int idx = blockIdx.x*256+threadIdx.x;
  if (idx >= BN_*64) return;
  int v = idx >> 6, c = idx & 63;
  int b = v >> 9, n = v & 511;
  float val = 0.f;
  if (c < 32)       val = ns[(size_t)b*NSROW_ + n*32 + c];
  else if (c == 32) val = (a[b]==n) ? 1.f : 0.f;
  sa[idx] = f2b(val);
}

// ---------------- LDS-tiled block-diagonal weight transpose ---------------

struct WtP { const float* Wr[4]; const float* Wn[4]; ushort* T[4]; };

__global__ __launch_bounds__(256) void k_wt_tr(WtP p) {
  int t = blockIdx.x;
  int s, base, KP, DINR, DINN, DOUTN, KOFF;
  if (t < 48)        { s=0; base=0;    KP=64;  DINR=33;  DINN=33;  DOUTN=128; KOFF=0;   }
  else if (t < 600)  { s=1; base=48;   KP=736; DINR=601; DINN=128; DOUTN=64;  KOFF=608; }
  else if (t < 1104) { s=2; base=600;  KP=672; DINR=601; DINN=64;  DOUTN=64;  KOFF=608; }
  else               { s=3; base=1104; KP=672; DINR=601; DINN=64;  DOUTN=32;  KOFF=608; }
  int ti = t - base;
  int kt = ti / 24, nt = ti - kt*24;
  int k0 = kt*32, n0 = nt*32;
  __shared__ float tile[32][33];
  int tid = threadIdx.x;
  int cc = tid & 31, rr = tid >> 5;
  #pragma unroll
  for (int it=0; it<4; it++) {
    int k = k0 + it*8 + rr;
    int n = n0 + cc;
    float v = 0.f;
    if (n < 640) { if (n < 601 && k < DINR) v = p.Wr[s][(size_t)k*601 + n]; }
    else { int nn = n-640, kk = k-KOFF;
           if (nn < DOUTN && kk >= 0 && kk < DINN) v = p.Wn[s][(size_t)kk*DOUTN + nn]; }
    tile[it*8+rr][cc] = v;
  }
  __syncthreads();
  #pragma unroll
  for (int it=0; it<4; it++) {
    int n = n0 + it*8 + rr;
    int k = k0 + cc;
    p.T[s][(size_t)n*KP + k] = f2b(tile[cc][it*8+rr]);
  }
}

// ---------------- MFMA bf16 GEMM, 64x128 tile + atomic final es/ed --------

__global__ __launch_bounds__(256) void k_gemm(const ushort* __restrict__ A,
                                              const ushort* __restrict__ Bt,
                                              ushort* __restrict__ C,
                                              float* __restrict__ esed, // es_r|ed_r|es_n|ed_n
                                              const float* __restrict__ asr,
                                              const float* __restrict__ adr,
                                              const float* __restrict__ asn,
                                              const float* __restrict__ adn,
                                              int Kpad, int dn) {
  __shared__ ushort Asm[64*32];
  __shared__ ushort Bsm[128*32];
  int tid = threadIdx.x;
  int rowBase = blockIdx.y * 64;
  int colBase = blockIdx.x * 128;
  int wave = tid >> 6, lane = tid & 63;
  int wr = (wave >> 1) * 32, wc = (wave & 1) * 64;
  int lm = lane & 15, lk = (lane >> 4) * 8;

  f32x4 acc[2][4];
  #pragma unroll
  for (int i=0;i<2;i++)
    #pragma unroll
    for (int j=0;j<4;j++) acc[i][j] = (f32x4){0.f,0.f,0.f,0.f};

  int t0 = tid, t1 = tid + 256;
  const ushort* Ag0 = A  + (size_t)(rowBase + (t0>>2))*Kpad + (t0&3)*8;
  const ushort* Bg0 = Bt + (size_t)(colBase + (t0>>2))*Kpad + (t0&3)*8;
  const ushort* Bg1 = Bt + (size_t)(colBase + (t1>>2))*Kpad + (t1&3)*8;
  ushort* Al0 = &Asm[t0*8];
  ushort* Bl0 = &Bsm[t0*8];
  ushort* Bl1 = &Bsm[t1*8];

  for (int k0 = 0; k0 < Kpad; k0 += 32) {
    gl_lds16(Ag0 + k0, Al0);
    gl_lds16(Bg0 + k0, Bl0);
    gl_lds16(Bg1 + k0, Bl1);
    __syncthreads();
    short8 af[2], bfr[4];
    #pragma unroll
    for (int i=0;i<2;i++) af[i]  = *(short8*)&Asm[(wr + i*16 + lm)*32 + lk];
    #pragma unroll
    for (int j=0;j<4;j++) bfr[j] = *(short8*)&Bsm[(wc + j*16 + lm)*32 + lk];
    #pragma unroll
    for (int i=0;i<2;i++)
      #pragma unroll
      for (int j=0;j<4;j++)
        acc[i][j] = __builtin_amdgcn_mfma_f32_16x16x32_bf16(af[i], bfr[j], acc[i][j], 0,0,0);
    __syncthreads();
  }

  float asv[4], adv[4];
  #pragma unroll
  for (int j=0;j<4;j++) {
    int col = colBase + wc + j*16 + lm;
    float s = 0.f, d = 0.f;
    if (col < 601)      { s = asr[col];     d = adr[col]; }
    else if (col >= 640 && col - 640 < dn) { s = asn[col-640]; d = adn[col-640]; }
    asv[j] = s; adv[j] = d;
  }
  int cr = lane >> 4;
  int ct2 = blockIdx.x*2 + (wc >> 6);          // 64-col tile 0..11
  float* esp = (ct2 < 10) ? esed : esed + 2*BN_;
  #pragma unroll
  for (int i=0;i<2;i++) {
    #pragma unroll
    for (int j=0;j<4;j++) {
      int col = colBase + wc + j*16 + lm;
      #pragma unroll
      for (int g=0; g<4; g++) {
        int row = rowBase + wr + i*16 + cr*4 + g;
        C[(size_t)row*HLD_ + col] = f2b(acc[i][j][g]);
      }
    }
    #pragma unroll
    for (int g=0; g<4; g++) {
      float se = 0.f, sd = 0.f;
      #pragma unroll
      for (int j=0;j<4;j++) { se += acc[i][j][g]*asv[j]; sd += acc[i][j][g]*adv[j]; }
      #pragma unroll
      for (int o=1;o<16;o<<=1) { se += __shfl_xor(se,o,64); sd += __shfl_xor(sd,o,64); }
      if (lm == 0) {
        int row = rowBase + wr + i*16 + cr*4 + g;
        atomicAdd(&esp[row], se);
        atomicAdd(&esp[BN_ + row], sd);
      }
    }
  }
}

// ---------------- combined softmax + aggregation (one wave per node) ------

__global__ __launch_bounds__(256) void k_agg(const ushort* __restrict__ h,
                                             const float* __restrict__ esed,
                                             const int* __restrict__ rowptr,
                                             const int* __restrict__ csr,
                                             const float* __restrict__ bias_r,
                                             const float* __restrict__ bias_n,
                                             ushort* __restrict__ g,
                                             int dn) {
  const float* es_r = esed;
  const float* ed_r = esed + BN_;
  const float* es_n = esed + 2*BN_;
  const float* ed_n = esed + 3*BN_;
  int wid = threadIdx.x>>6, lane = threadIdx.x&63;
  int bid = blockIdx.x;
  int xcd = bid & 7, slot = bid >> 3;
  int graph = xcd + ((slot >> 7) << 3);
  int v = graph*512 + (slot & 127)*4 + wid;
  int s0 = rowptr[v], e0 = rowptr[v+1];
  int deg = e0 - s0;
  float edr = ed_r[v], edn = ed_n[v];

  int ch0 = lane, ch1 = lane + 64;
  bool a1 = ch1 < 96;
  bool c1r = ch1 < 80;
  float acc0[8], acc1[8];
  #pragma unroll
  for (int q=0;q<8;q++){ acc0[q]=0.f; acc1[q]=0.f; }

  if (deg <= 64) {
    bool has = lane < deg;
    int u = 0; float er = -__builtin_inff(), en = -__builtin_inff();
    if (has) {
      u = csr[s0 + lane];
      er = es_r[u] + edr; er = er > 0.f ? er : 0.2f*er;
      en = es_n[u] + edn; en = en > 0.f ? en : 0.2f*en;
    }
    float mr = er, mn = en;
    #pragma unroll
    for (int o=32;o;o>>=1) { mr = fmaxf(mr, __shfl_xor(mr,o,64)); mn = fmaxf(mn, __shfl_xor(mn,o,64)); }
    float pr = has ? __expf(er - mr) : 0.f;
    float pn = has ? __expf(en - mn) : 0.f;
    float dr = pr, dnm = pn;
    #pragma unroll
    for (int o=32;o;o>>=1) { dr += __shfl_xor(dr,o,64); dnm += __shfl_xor(dnm,o,64); }
    pr *= 1.f/(dr + 1e-16f);
    pn *= 1.f/(dnm + 1e-16f);

    for (int t0 = 0; t0 < deg; t0 += 4) {
      int nt = deg - t0; if (nt > 4) nt = 4;
      short8 va[4], vb[4];
      float w0[4], w1[4];
      #pragma unroll
      for (int q=0;q<4;q++) {
        if (q < nt) {
          int uu = __shfl(u, t0+q, 64);
          w0[q] = __shfl(pr, t0+q, 64);
          w1[q] = __shfl(pn, t0+q, 64);
          const ushort* hp = h + (size_t)uu*HLD_;
          va[q] = *(const short8*)&hp[ch0*8];
          vb[q] = a1 ? *(const short8*)&hp[ch1*8] : short8{};
        } else {
          w0[q] = 0.f; w1[q] = 0.f; va[q] = short8{}; vb[q] = short8{};
        }
      }
      #pragma unroll
      for (int q=0;q<4;q++) {
        #pragma unroll
        for (int r=0;r<8;r++) acc0[r] += w0[q] * b2f((ushort)va[q][r]);
        if (a1) {
          float wv = c1r ? w0[q] : w1[q];
          #pragma unroll
          for (int r=0;r<8;r++) acc1[r] += wv * b2f((ushort)vb[q][r]);
        }
      }
    }
  } else {
    float mr = -__builtin_inff(), mn = -__builtin_inff();
    for (int j = s0 + lane; j < e0; j += 64) {
      int u = csr[j];
      float er = es_r[u] + edr; er = er>0.f?er:0.2f*er;
      float en = es_n[u] + edn; en = en>0.f?en:0.2f*en;
      mr = fmaxf(mr, er); mn = fmaxf(mn, en);
    }
    #pragma unroll
    for (int o=32;o;o>>=1) { mr=fmaxf(mr,__shfl_xor(mr,o,64)); mn=fmaxf(mn,__shfl_xor(mn,o,64)); }
    float dr=0.f, dnm=0.f;
    for (int j = s0 + lane; j < e0; j += 64) {
      int u = csr[j];
      float er = es_r[u] + edr; er = er>0.f?er:0.2f*er;
      float en = es_n[u] + edn; en = en>0.f?en:0.2f*en;
      dr += __expf(er-mr); dnm += __expf(en-mn);
    }
    #pragma unroll
    for (int o=32;o;o>>=1) { dr+=__shfl_xor(dr,o,64); dnm+=__shfl_xor(dnm,o,64); }
    float ir = 1.f/(dr+1e-16f), in_ = 1.f/(dnm+1e-16f);
    for (int j = s0; j < e0; ++j) {
      int uu = csr[j];
      float er = es_r[uu] + edr; er = er>0.f?er:0.2f*er;
      float en = es_n[uu] + edn; en = en>0.f?en:0.2f*en;
      float wr2 = __expf(er-mr)*ir, wn2 = __expf(en-mn)*in_;
      const ushort* hp = h + (size_t)uu*HLD_;
      short8 hv = *(const short8*)&hp[ch0*8];
      #pragma unroll
      for (int q=0;q<8;q++) acc0[q] += wr2 * b2f((ushort)hv[q]);
      if (a1) {
        short8 hv2 = *(const short8*)&hp[ch1*8];
        float wv = c1r ? wr2 : wn2;
        #pragma unroll
        for (int q=0;q<8;q++) acc1[q] += wv * b2f((ushort)hv2[q]);
      }
    }
  }

  ushort* gv = g + (size_t)v*HLD_;
  {
    int cb = ch0*8;
    short8 ov;
    #pragma unroll
    for (int q=0;q<8;q++) ov[q] = (short)f2b(acc0[q] + bias_r[cb+q]);
    *(short8*)&gv[cb] = ov;
  }
  if (a1) {
    int cb = ch1*8;
    short8 ov;
    #pragma unroll
    for (int q=0;q<8;q++) {
      int c = cb+q;
      float val;
      if (c < 601)                         val = acc1[q] + bias_r[c];
      else if (c >= 640 && (c-640) < dn)   val = acc1[q] + bias_n[c-640];
      else                                 val = 0.f;
      ov[q] = (short)f2b(val);
    }
    *(short8*)&gv[cb] = ov;
  }
}

// ---------------- LN stats partials (z=4 chunks of 128 rows) --------------

__global__ __launch_bounds__(256) void k_ln_stats(const ushort* __restrict__ g,
                                                  float* __restrict__ st) {
  int b = blockIdx.y, z = blockIdx.z; int n0 = z*128;
  int lc = threadIdx.x & 63, r0 = threadIdx.x >> 6;
  int c = blockIdx.x*64 + lc;
  float s=0.f, q=0.f;
  #pragma unroll 4
  for (int i=0;i<32;i++) {
    int n = n0 + r0*32 + i;
    float x = b2f(g[(size_t)(b*N_+n)*HLD_ + c]);
    s+=x; q+=x*x;
  }
  __shared__ float S[4][64], Q[4][64];
  S[r0][lc]=s; Q[r0][lc]=q; __syncthreads();
  if (r0==0) {
    st[((size_t)(z*2+0)*B_ + b)*HLD_ + c] = S[0][lc]+S[1][lc]+S[2][lc]+S[3][lc];
    st[((size_t)(z*2+1)*B_ + b)*HLD_ + c] = Q[0][lc]+Q[1][lc]+Q[2][lc]+Q[3][lc];
  }
}

// ---------------- LN apply + ReLU (finalize folded; col pair x 16 rows) ---

__global__ __launch_bounds__(256) void k_ln_apply(const ushort* __restrict__ g,
                                                  const float* __restrict__ st,
                                                  const float* __restrict__ scr,
                                                  const float* __restrict__ ofr,
                                                  const float* __restrict__ scn,
                                                  const float* __restrict__ ofn,
                                                  ushort* __restrict__ xb,
                                                  int dn, int Kpad) {
  int tid = threadIdx.x;
  int pp = blockIdx.x*128 + (tid & 127);
  int c0 = pp*2;
  if (c0 >= Kpad) return;
  int vbase = blockIdx.y*16;
  int b = vbase >> 9;
  float mv[2], av[2];
  #pragma unroll
  for (int q=0;q<2;q++) {
    int c = c0+q;
    int cs; bool valid; float scale, offs;
    if (c < 608) { cs = c; valid = c < 601;
                   scale = valid ? scr[c] : 0.f; offs = valid ? ofr[c] : 0.f; }
    else { int cn = c - 608; cs = 640 + cn; valid = cn < dn;
           scale = valid ? scn[cn] : 0.f; offs = valid ? ofn[cn] : 0.f; }
    float mul = 0.f, add = 0.f;
    if (valid) {
      float s=0.f, qq=0.f;
      #pragma unroll
      for (int z=0;z<4;z++) {
        s  += st[((size_t)(z*2+0)*B_ + b)*HLD_ + cs];
        qq += st[((size_t)(z*2+1)*B_ + b)*HLD_ + cs];
      }
      float mu = s*(1.f/N_);
      float var = qq*(1.f/N_) - mu*mu;
      float rs = rsqrtf(var+1e-5f);
      mul = rs*scale;
      add = offs - mu*rs*scale;
    }
    mv[q] = mul; av[q] = add;
  }
  int cs0 = (c0 < 608) ? c0 : 640 + (c0 - 608);
  for (int i = tid >> 7; i < 16; i += 2) {
    int v = vbase + i;
    uint gg = *(const uint*)&g[(size_t)v*HLD_ + cs0];
    float x0 = b2f((ushort)(gg & 0xFFFFu));
    float x1 = b2f((ushort)(gg >> 16));
    float y0 = x0*mv[0] + av[0]; y0 = y0 > 0.f ? y0 : 0.f;
    float y1 = x1*mv[1] + av[1]; y1 = y1 > 0.f ? y1 : 0.f;
    *(uint*)&xb[(size_t)v*Kpad + c0] = ((uint)f2b(y1) << 16) | f2b(y0);
  }
}

// ---------------- reward: sum over nodes (slot partials) ----------------

__global__ __launch_bounds__(256) void k_rsum(const ushort* __restrict__ g,
                                              float* __restrict__ rsp) {
  int b = blockIdx.y, z = blockIdx.z; int n0 = z*64;
  int lc = threadIdx.x & 63, r0 = threadIdx.x>>6;
  int c = blockIdx.x*64 + lc;
  float s = 0.f;
  if (c < FSS_) {
    #pragma unroll 4
    for (int i=0;i<16;i++) {
      int n = n0 + r0*16 + i;
      s += b2f(g[(size_t)(b*N_+n)*HLD_ + c]);
    }
  }
  __shared__ float S[4][64];
  S[r0][lc]=s; __syncthreads();
  if (r0==0 && c<FSS_)
    rsp[((size_t)z*B_ + b)*FSS_ + c] = S[0][lc]+S[1][lc]+S[2][lc]+S[3][lc];
}

// ---------------- final: reward finalize + ns_new assembly ----------------

__global__ __launch_bounds__(256) void k_final(const float* __restrict__ rsp,
                                               const ushort* __restrict__ g,
                                               const float* __restrict__ ns,
                                               float* __restrict__ out) {
  int idx = blockIdx.x*256+threadIdx.x;
  if (idx < OUT_R_) {
    int b = idx / FSS_, c = idx - b*FSS_;
    float s = 0.f;
    #pragma unroll
    for (int z=0;z<8;z++) s += rsp[((size_t)z*B_ + b)*FSS_ + c];
    out[idx] = s;
  } else {
    int j2 = idx - OUT_R_;
    if (j2 >= B_*NSROW_) return;
    int b = j2 / NSROW_; int j = j2 - b*NSROW_;
    float v;
    if (j < SLEFT_) {
      int n = j >> 5, c = j & 31;
      v = b2f(g[(size_t)(b*N_+n)*HLD_ + 640 + c]);
    } else {
      v = ns[(size_t)b*NSROW_ + j];
    }
    out[idx] = v;
  }
}

// ---------------- host driver ----------------

extern "C" void kernel_launch(void* const* d_in, const int* in_sizes, int n_in,
                              void* d_out, int out_size, void* d_ws, size_t ws_size,
                              hipStream_t stream) {
  const float* ns = (const float*)d_in[0];
  const int*   a  = (const int*)d_in[1];

  const float *W[4], *As[4], *Ad[4], *Bb[4], *Sc[3], *Of[3];
  const float *rW[4], *rAs[4], *rAd[4], *rBb[4], *rSc[3], *rOf[3];
  int p = 2;
  for (int i=0;i<4;i++){
    W[i]=(const float*)d_in[p++]; As[i]=(const float*)d_in[p++];
    Ad[i]=(const float*)d_in[p++]; Bb[i]=(const float*)d_in[p++];
    if (i<3){ Sc[i]=(const float*)d_in[p++]; Of[i]=(const float*)d_in[p++]; }
  }
  for (int i=0;i<4;i++){
    rW[i]=(const float*)d_in[p++]; rAs[i]=(const float*)d_in[p++];
    rAd[i]=(const float*)d_in[p++]; rBb[i]=(const float*)d_in[p++];
    if (i<3){ rSc[i]=(const float*)d_in[p++]; rOf[i]=(const float*)d_in[p++]; }
  }

  char* w = (char*)d_ws;
  auto carve = [&](size_t bytes)->void* {
    void* r = (void*)w;
    w += (bytes + 255) & ~(size_t)255;
    return r;
  };
  ushort* xb   = (ushort*)carve((size_t)BN_*736*2);
  ushort* hbuf = (ushort*)carve((size_t)BN_*HLD_*2);
  ushort* gbuf = (ushort*)carve((size_t)BN_*HLD_*2);
  ushort* sabf = (ushort*)carve((size_t)BN_*64*2);
  // zero-region: cnt | fill | esed[4 layers], one memset covers all
  int* cnt     = (int*)carve((size_t)(2*BN_ + 4*4*BN_)*4);
  int* fill    = cnt + BN_;
  float* esedL = (float*)(cnt + 2*BN_);              // 4 x [4*BN]
  float* stp   = (float*)carve((size_t)8*B_*HLD_*4);
  float* rsp   = (float*)carve((size_t)8*B_*FSS_*4);
  int* src_i   = (int*)carve((size_t)BE_*4);
  int* dst_i   = (int*)carve((size_t)BE_*4);
  int* rowptr  = (int*)carve((size_t)(BN_+1)*4);
  int* csr_src = (int*)carve((size_t)BE_*4);
  ushort* Wt[4];
  Wt[0] = (ushort*)carve((size_t)768*64*2);
  Wt[1] = (ushort*)carve((size_t)768*736*2);
  Wt[2] = (ushort*)carve((size_t)768*672*2);
  Wt[3] = (ushort*)carve((size_t)768*672*2);

  float* out = (float*)d_out;

  hipMemsetAsync(cnt, 0, (size_t)(2*BN_ + 16*BN_)*4, stream);

  k_indices<<<(BE_+255)/256, 256, 0, stream>>>(ns, src_i, dst_i, cnt);
  k_scan<<<1, 1024, 0, stream>>>(cnt, rowptr);
  k_scatter<<<(BE_+255)/256, 256, 0, stream>>>(src_i, dst_i, rowptr, fill, csr_src);
  k_sa<<<(BN_*64+255)/256, 256, 0, stream>>>(ns, a, sabf);

  WtP wtp;
  for (int i=0;i<4;i++){ wtp.Wr[i]=rW[i]; wtp.Wn[i]=W[i]; wtp.T[i]=Wt[i]; }
  k_wt_tr<<<1608, 256, 0, stream>>>(wtp);

  dim3 ggrid(6, BN_/64);   // 768 blocks

  const ushort* xin[4] = { sabf, xb, xb, xb };
  int Kp[4]  = { 64, 736, 672, 672 };
  int dns[4] = { 128, 64, 64, 32 };

  for (int L=0; L<4; ++L) {
    float* esed = esedL + (size_t)L*4*BN_;
    k_gemm<<<ggrid, 256, 0, stream>>>(xin[L], Wt[L], hbuf, esed,
                                      rAs[L], rAd[L], As[L], Ad[L], Kp[L], dns[L]);
    k_agg<<<BN_/4, 256, 0, stream>>>(hbuf, esed, rowptr, csr_src,
                                     rBb[L], Bb[L], gbuf, dns[L]);
    if (L < 3) {
      k_ln_stats<<<dim3(12, B_, 4), 256, 0, stream>>>(gbuf, stp);
      int Kpn = (L==0) ? 736 : 672;
      k_ln_apply<<<dim3(3, BN_/16), 256, 0, stream>>>(gbuf, stp,
                  rSc[L], rOf[L], Sc[L], Of[L], xb, dns[L], Kpn);
    }
  }

  k_rsum<<<dim3(10, B_, 8), 256, 0, stream>>>(gbuf, rsp);
  k_final<<<(OUT_R_ + B_*NSROW_ + 255)/256, 256, 0, stream>>>(rsp, gbuf, ns, out);
}

// Round 15
// 378.526 us; speedup vs baseline: 3.6996x; 1.0159x over previous
//
#include <hip/hip_runtime.h>
#include <math.h>

#define B_ 16
#define N_ 512
#define D_ 32
#define E_ 8176
#define SLEFT_ 16384
#define FSS_ 601
#define BN_ (B_*N_)            // 8192
#define BE_ (B_*E_)            // 130816
#define NSROW_ (SLEFT_ + 2*E_) // 32736
#define OUT_R_ (B_*FSS_)       // 9616
#define HLD_ 768               // combined width: reward 0..639, next 640..767

typedef __attribute__((ext_vector_type(8))) short short8;
typedef __attribute__((ext_vector_type(4))) float f32x4;

typedef __attribute__((address_space(3))) uint lds_uint;
typedef __attribute__((address_space(1))) const uint g_uint;

__device__ __forceinline__ void gl_lds16(const ushort* gp, ushort* lp) {
  __builtin_amdgcn_global_load_lds((g_uint*)gp, (lds_uint*)lp, 16, 0, 0);
}

__device__ __forceinline__ ushort f2b(float f) {
  uint u = __builtin_bit_cast(uint, f);
  u += 0x7FFFu + ((u >> 16) & 1u);
  return (ushort)(u >> 16);
}
__device__ __forceinline__ float b2f(ushort h) {
  return __builtin_bit_cast(float, ((uint)h) << 16);
}

// ---------------- index / CSR build ----------------

__global__ __launch_bounds__(256) void k_indices(const float* __restrict__ ns,
                                                 int* __restrict__ src_i,
                                                 int* __restrict__ dst_i,
                                                 int* __restrict__ cnt) {
  int idx = blockIdx.x*256 + threadIdx.x;
  if (idx >= BE_) return;
  int b = idx / E_;
  int j = idx - b*E_;
  const float* row = ns + (size_t)b*NSROW_;
  int s = (int)row[SLEFT_ + j];
  int r = (int)row[SLEFT_ + E_ + j];
  src_i[idx] = b*N_ + s;
  int dst = b*N_ + r;
  dst_i[idx] = dst;
  atomicAdd(&cnt[dst], 1);
}

__global__ __launch_bounds__(1024) void k_scan(const int* __restrict__ cnt,
                                               int* __restrict__ rowptr) {
  __shared__ int part[1024];
  int t = threadIdx.x;
  int base = t*8;
  int loc[8]; int s = 0;
  #pragma unroll
  for (int i=0;i<8;i++){ loc[i]=cnt[base+i]; s+=loc[i]; }
  part[t]=s; __syncthreads();
  for (int off=1; off<1024; off<<=1) {
    int v = (t>=off)?part[t-off]:0;
    __syncthreads();
    part[t]+=v;
    __syncthreads();
  }
  int ex = (t==0)?0:part[t-1];
  #pragma unroll
  for (int i=0;i<8;i++){ rowptr[base+i]=ex; ex+=loc[i]; }
  if (t==1023) rowptr[BN_]=ex;
}

__global__ __launch_bounds__(256) void k_scatter(const int* __restrict__ src_i,
                                                 const int* __restrict__ dst_i,
                                                 const int* __restrict__ rowptr,
                                                 int* __restrict__ fill,
                                                 int* __restrict__ csr_src) {
  int idx = blockIdx.x*256+threadIdx.x;
  if (idx>=BE_) return;
  int dst = dst_i[idx];
  int pos = rowptr[dst] + atomicAdd(&fill[dst],1);
  csr_src[pos] = src_i[idx];
}

// ---------------- sa (bf16, padded to K=64) ----------------

__global__ __launch_bounds__(256) void k_sa(const float* __restrict__ ns,
                                            const int* __restrict__ a,
                                            ushort* __restrict__ sa) {
  int idx = blockIdx.x*256+threadIdx.x;
  if (idx >= BN_*64) return;
  int v = idx >> 6, c = idx & 63;
  int b = v >> 9, n = v & 511;
  float val = 0.f;
  if (c < 32)       val = ns[(size_t)b*NSROW_ + n*32 + c];
  else if (c == 32) val = (a[b]==n) ? 1.f : 0.f;
  sa[idx] = f2b(val);
}

// ---------------- LDS-tiled block-diagonal weight transpose ---------------

struct WtP { const float* Wr[4]; const float* Wn[4]; ushort* T[4]; };

__global__ __launch_bounds__(256) void k_wt_tr(WtP p) {
  int t = blockIdx.x;
  int s, base, KP, DINR, DINN, DOUTN, KOFF;
  if (t < 48)        { s=0; base=0;    KP=64;  DINR=33;  DINN=33;  DOUTN=128; KOFF=0;   }
  else if (t < 600)  { s=1; base=48;   KP=736; DINR=601; DINN=128; DOUTN=64;  KOFF=608; }
  else if (t < 1104) { s=2; base=600;  KP=672; DINR=601; DINN=64;  DOUTN=64;  KOFF=608; }
  else               { s=3; base=1104; KP=672; DINR=601; DINN=64;  DOUTN=32;  KOFF=608; }
  int ti = t - base;
  int kt = ti / 24, nt = ti - kt*24;
  int k0 = kt*32, n0 = nt*32;
  __shared__ float tile[32][33];
  int tid = threadIdx.x;
  int cc = tid & 31, rr = tid >> 5;
  #pragma unroll
  for (int it=0; it<4; it++) {
    int k = k0 + it*8 + rr;
    int n = n0 + cc;
    float v = 0.f;
    if (n < 640) { if (n < 601 && k < DINR) v = p.Wr[s][(size_t)k*601 + n]; }
    else { int nn = n-640, kk = k-KOFF;
           if (nn < DOUTN && kk >= 0 && kk < DINN) v = p.Wn[s][(size_t)kk*DOUTN + nn]; }
    tile[it*8+rr][cc] = v;
  }
  __syncthreads();
  #pragma unroll
  for (int it=0; it<4; it++) {
    int n = n0 + it*8 + rr;
    int k = k0 + cc;
    p.T[s][(size_t)n*KP + k] = f2b(tile[cc][it*8+rr]);
  }
}

// ---------------- MFMA bf16 GEMM, 64x128 tile + atomic final es/ed --------
// K-range split: col-blocks 0..4 (reward cols) loop k in [0, kRewEnd);
// col-block 5 (next-head cols) loops k in [kNextBeg, Kpad). Both heads'
// weight blocks are zero outside their range, so results are exact.

__global__ __launch_bounds__(256) void k_gemm(const ushort* __restrict__ A,
                                              const ushort* __restrict__ Bt,
                                              ushort* __restrict__ C,
                                              float* __restrict__ esed, // es_r|ed_r|es_n|ed_n
                                              const float* __restrict__ asr,
                                              const float* __restrict__ adr,
                                              const float* __restrict__ asn,
                                              const float* __restrict__ adn,
                                              int Kpad, int dn,
                                              int kRewEnd, int kNextBeg) {
  __shared__ ushort Asm[64*32];
  __shared__ ushort Bsm[128*32];
  int tid = threadIdx.x;
  int rowBase = blockIdx.y * 64;
  int colBase = blockIdx.x * 128;
  int kBeg = (blockIdx.x == 5) ? kNextBeg : 0;
  int kEnd = (blockIdx.x == 5) ? Kpad : kRewEnd;
  int wave = tid >> 6, lane = tid & 63;
  int wr = (wave >> 1) * 32, wc = (wave & 1) * 64;
  int lm = lane & 15, lk = (lane >> 4) * 8;

  f32x4 acc[2][4];
  #pragma unroll
  for (int i=0;i<2;i++)
    #pragma unroll
    for (int j=0;j<4;j++) acc[i][j] = (f32x4){0.f,0.f,0.f,0.f};

  int t0 = tid, t1 = tid + 256;
  const ushort* Ag0 = A  + (size_t)(rowBase + (t0>>2))*Kpad + (t0&3)*8;
  const ushort* Bg0 = Bt + (size_t)(colBase + (t0>>2))*Kpad + (t0&3)*8;
  const ushort* Bg1 = Bt + (size_t)(colBase + (t1>>2))*Kpad + (t1&3)*8;
  ushort* Al0 = &Asm[t0*8];
  ushort* Bl0 = &Bsm[t0*8];
  ushort* Bl1 = &Bsm[t1*8];

  for (int k0 = kBeg; k0 < kEnd; k0 += 32) {
    gl_lds16(Ag0 + k0, Al0);
    gl_lds16(Bg0 + k0, Bl0);
    gl_lds16(Bg1 + k0, Bl1);
    __syncthreads();
    short8 af[2], bfr[4];
    #pragma unroll
    for (int i=0;i<2;i++) af[i]  = *(short8*)&Asm[(wr + i*16 + lm)*32 + lk];
    #pragma unroll
    for (int j=0;j<4;j++) bfr[j] = *(short8*)&Bsm[(wc + j*16 + lm)*32 + lk];
    #pragma unroll
    for (int i=0;i<2;i++)
      #pragma unroll
      for (int j=0;j<4;j++)
        acc[i][j] = __builtin_amdgcn_mfma_f32_16x16x32_bf16(af[i], bfr[j], acc[i][j], 0,0,0);
    __syncthreads();
  }

  float asv[4], adv[4];
  #pragma unroll
  for (int j=0;j<4;j++) {
    int col = colBase + wc + j*16 + lm;
    float s = 0.f, d = 0.f;
    if (col < 601)      { s = asr[col];     d = adr[col]; }
    else if (col >= 640 && col - 640 < dn) { s = asn[col-640]; d = adn[col-640]; }
    asv[j] = s; adv[j] = d;
  }
  int cr = lane >> 4;
  int ct2 = blockIdx.x*2 + (wc >> 6);          // 64-col tile 0..11
  float* esp = (ct2 < 10) ? esed : esed + 2*BN_;
  #pragma unroll
  for (int i=0;i<2;i++) {
    #pragma unroll
    for (int j=0;j<4;j++) {
      int col = colBase + wc + j*16 + lm;
      #pragma unroll
      for (int g=0; g<4; g++) {
        int row = rowBase + wr + i*16 + cr*4 + g;
        C[(size_t)row*HLD_ + col] = f2b(acc[i][j][g]);
      }
    }
    #pragma unroll
    for (int g=0; g<4; g++) {
      float se = 0.f, sd = 0.f;
      #pragma unroll
      for (int j=0;j<4;j++) { se += acc[i][j][g]*asv[j]; sd += acc[i][j][g]*adv[j]; }
      #pragma unroll
      for (int o=1;o<16;o<<=1) { se += __shfl_xor(se,o,64); sd += __shfl_xor(sd,o,64); }
      if (lm == 0) {
        int row = rowBase + wr + i*16 + cr*4 + g;
        atomicAdd(&esp[row], se);
        atomicAdd(&esp[BN_ + row], sd);
      }
    }
  }
}

// ---------------- combined softmax + aggregation (one wave per node) ------

__global__ __launch_bounds__(256) void k_agg(const ushort* __restrict__ h,
                                             const float* __restrict__ esed,
                                             const int* __restrict__ rowptr,
                                             const int* __restrict__ csr,
                                             const float* __restrict__ bias_r,
                                             const float* __restrict__ bias_n,
                                             ushort* __restrict__ g,
                                             int dn) {
  const float* es_r = esed;
  const float* ed_r = esed + BN_;
  const float* es_n = esed + 2*BN_;
  const float* ed_n = esed + 3*BN_;
  int wid = threadIdx.x>>6, lane = threadIdx.x&63;
  int bid = blockIdx.x;
  int xcd = bid & 7, slot = bid >> 3;
  int graph = xcd + ((slot >> 7) << 3);
  int v = graph*512 + (slot & 127)*4 + wid;
  int s0 = rowptr[v], e0 = rowptr[v+1];
  int deg = e0 - s0;
  float edr = ed_r[v], edn = ed_n[v];

  int ch0 = lane, ch1 = lane + 64;
  bool a1 = ch1 < 96;
  bool c1r = ch1 < 80;
  float acc0[8], acc1[8];
  #pragma unroll
  for (int q=0;q<8;q++){ acc0[q]=0.f; acc1[q]=0.f; }

  if (deg <= 64) {
    bool has = lane < deg;
    int u = 0; float er = -__builtin_inff(), en = -__builtin_inff();
    if (has) {
      u = csr[s0 + lane];
      er = es_r[u] + edr; er = er > 0.f ? er : 0.2f*er;
      en = es_n[u] + edn; en = en > 0.f ? en : 0.2f*en;
    }
    float mr = er, mn = en;
    #pragma unroll
    for (int o=32;o;o>>=1) { mr = fmaxf(mr, __shfl_xor(mr,o,64)); mn = fmaxf(mn, __shfl_xor(mn,o,64)); }
    float pr = has ? __expf(er - mr) : 0.f;
    float pn = has ? __expf(en - mn) : 0.f;
    float dr = pr, dnm = pn;
    #pragma unroll
    for (int o=32;o;o>>=1) { dr += __shfl_xor(dr,o,64); dnm += __shfl_xor(dnm,o,64); }
    pr *= 1.f/(dr + 1e-16f);
    pn *= 1.f/(dnm + 1e-16f);

    for (int t0 = 0; t0 < deg; t0 += 4) {
      int nt = deg - t0; if (nt > 4) nt = 4;
      short8 va[4], vb[4];
      float w0[4], w1[4];
      #pragma unroll
      for (int q=0;q<4;q++) {
        if (q < nt) {
          int uu = __shfl(u, t0+q, 64);
          w0[q] = __shfl(pr, t0+q, 64);
          w1[q] = __shfl(pn, t0+q, 64);
          const ushort* hp = h + (size_t)uu*HLD_;
          va[q] = *(const short8*)&hp[ch0*8];
          vb[q] = a1 ? *(const short8*)&hp[ch1*8] : short8{};
        } else {
          w0[q] = 0.f; w1[q] = 0.f; va[q] = short8{}; vb[q] = short8{};
        }
      }
      #pragma unroll
      for (int q=0;q<4;q++) {
        #pragma unroll
        for (int r=0;r<8;r++) acc0[r] += w0[q] * b2f((ushort)va[q][r]);
        if (a1) {
          float wv = c1r ? w0[q] : w1[q];
          #pragma unroll
          for (int r=0;r<8;r++) acc1[r] += wv * b2f((ushort)vb[q][r]);
        }
      }
    }
  } else {
    float mr = -__builtin_inff(), mn = -__builtin_inff();
    for (int j = s0 + lane; j < e0; j += 64) {
      int u = csr[j];
      float er = es_r[u] + edr; er = er>0.f?er:0.2f*er;
      float en = es_n[u] + edn; en = en>0.f?en:0.2f*en;
      mr = fmaxf(mr, er); mn = fmaxf(mn, en);
    }
    #pragma unroll
    for (int o=32;o;o>>=1) { mr=fmaxf(mr,__shfl_xor(mr,o,64)); mn=fmaxf(mn,__shfl_xor(mn,o,64)); }
    float dr=0.f, dnm=0.f;
    for (int j = s0 + lane; j < e0; j += 64) {
      int u = csr[j];
      float er = es_r[u] + edr; er = er>0.f?er:0.2f*er;
      float en = es_n[u] + edn; en = en>0.f?en:0.2f*en;
      dr += __expf(er-mr); dnm += __expf(en-mn);
    }
    #pragma unroll
    for (int o=32;o;o>>=1) { dr+=__shfl_xor(dr,o,64); dnm+=__shfl_xor(dnm,o,64); }
    float ir = 1.f/(dr+1e-16f), in_ = 1.f/(dnm+1e-16f);
    for (int j = s0; j < e0; ++j) {
      int uu = csr[j];
      float er = es_r[uu] + edr; er = er>0.f?er:0.2f*er;
      float en = es_n[uu] + edn; en = en>0.f?en:0.2f*en;
      float wr2 = __expf(er-mr)*ir, wn2 = __expf(en-mn)*in_;
      const ushort* hp = h + (size_t)uu*HLD_;
      short8 hv = *(const short8*)&hp[ch0*8];
      #pragma unroll
      for (int q=0;q<8;q++) acc0[q] += wr2 * b2f((ushort)hv[q]);
      if (a1) {
        short8 hv2 = *(const short8*)&hp[ch1*8];
        float wv = c1r ? wr2 : wn2;
        #pragma unroll
        for (int q=0;q<8;q++) acc1[q] += wv * b2f((ushort)hv2[q]);
      }
    }
  }

  ushort* gv = g + (size_t)v*HLD_;
  {
    int cb = ch0*8;
    short8 ov;
    #pragma unroll
    for (int q=0;q<8;q++) ov[q] = (short)f2b(acc0[q] + bias_r[cb+q]);
    *(short8*)&gv[cb] = ov;
  }
  if (a1) {
    int cb = ch1*8;
    short8 ov;
    #pragma unroll
    for (int q=0;q<8;q++) {
      int c = cb+q;
      float val;
      if (c < 601)                         val = acc1[q] + bias_r[c];
      else if (c >= 640 && (c-640) < dn)   val = acc1[q] + bias_n[c-640];
      else                                 val = 0.f;
      ov[q] = (short)f2b(val);
    }
    *(short8*)&gv[cb] = ov;
  }
}

// ---------------- LN stats partials (z=4 chunks of 128 rows) --------------

__global__ __launch_bounds__(256) void k_ln_stats(const ushort* __restrict__ g,
                                                  float* __restrict__ st) {
  int b = blockIdx.y, z = blockIdx.z; int n0 = z*128;
  int lc = threadIdx.x & 63, r0 = threadIdx.x >> 6;
  int c = blockIdx.x*64 + lc;
  float s=0.f, q=0.f;
  #pragma unroll 4
  for (int i=0;i<32;i++) {
    int n = n0 + r0*32 + i;
    float x = b2f(g[(size_t)(b*N_+n)*HLD_ + c]);
    s+=x; q+=x*x;
  }
  __shared__ float S[4][64], Q[4][64];
  S[r0][lc]=s; Q[r0][lc]=q; __syncthreads();
  if (r0==0) {
    st[((size_t)(z*2+0)*B_ + b)*HLD_ + c] = S[0][lc]+S[1][lc]+S[2][lc]+S[3][lc];
    st[((size_t)(z*2+1)*B_ + b)*HLD_ + c] = Q[0][lc]+Q[1][lc]+Q[2][lc]+Q[3][lc];
  }
}

// ---------------- LN apply + ReLU (finalize folded; col pair x 16 rows) ---

__global__ __launch_bounds__(256) void k_ln_apply(const ushort* __restrict__ g,
                                                  const float* __restrict__ st,
                                                  const float* __restrict__ scr,
                                                  const float* __restrict__ ofr,
                                                  const float* __restrict__ scn,
                                                  const float* __restrict__ ofn,
                                                  ushort* __restrict__ xb,
                                                  int dn, int Kpad) {
  int tid = threadIdx.x;
  int pp = blockIdx.x*128 + (tid & 127);
  int c0 = pp*2;
  if (c0 >= Kpad) return;
  int vbase = blockIdx.y*16;
  int b = vbase >> 9;
  float mv[2], av[2];
  #pragma unroll
  for (int q=0;q<2;q++) {
    int c = c0+q;
    int cs; bool valid; float scale, offs;
    if (c < 608) { cs = c; valid = c < 601;
                   scale = valid ? scr[c] : 0.f; offs = valid ? ofr[c] : 0.f; }
    else { int cn = c - 608; cs = 640 + cn; valid = cn < dn;
           scale = valid ? scn[cn] : 0.f; offs = valid ? ofn[cn] : 0.f; }
    float mul = 0.f, add = 0.f;
    if (valid) {
      float s=0.f, qq=0.f;
      #pragma unroll
      for (int z=0;z<4;z++) {
        s  += st[((size_t)(z*2+0)*B_ + b)*HLD_ + cs];
        qq += st[((size_t)(z*2+1)*B_ + b)*HLD_ + cs];
      }
      float mu = s*(1.f/N_);
      float var = qq*(1.f/N_) - mu*mu;
      float rs = rsqrtf(var+1e-5f);
      mul = rs*scale;
      add = offs - mu*rs*scale;
    }
    mv[q] = mul; av[q] = add;
  }
  int cs0 = (c0 < 608) ? c0 : 640 + (c0 - 608);
  for (int i = tid >> 7; i < 16; i += 2) {
    int v = vbase + i;
    uint gg = *(const uint*)&g[(size_t)v*HLD_ + cs0];
    float x0 = b2f((ushort)(gg & 0xFFFFu));
    float x1 = b2f((ushort)(gg >> 16));
    float y0 = x0*mv[0] + av[0]; y0 = y0 > 0.f ? y0 : 0.f;
    float y1 = x1*mv[1] + av[1]; y1 = y1 > 0.f ? y1 : 0.f;
    *(uint*)&xb[(size_t)v*Kpad + c0] = ((uint)f2b(y1) << 16) | f2b(y0);
  }
}

// ---------------- reward: sum over nodes (slot partials) ----------------

__global__ __launch_bounds__(256) void k_rsum(const ushort* __restrict__ g,
                                              float* __restrict__ rsp) {
  int b = blockIdx.y, z = blockIdx.z; int n0 = z*64;
  int lc = threadIdx.x & 63, r0 = threadIdx.x>>6;
  int c = blockIdx.x*64 + lc;
  float s = 0.f;
  if (c < FSS_) {
    #pragma unroll 4
    for (int i=0;i<16;i++) {
      int n = n0 + r0*16 + i;
      s += b2f(g[(size_t)(b*N_+n)*HLD_ + c]);
    }
  }
  __shared__ float S[4][64];
  S[r0][lc]=s; __syncthreads();
  if (r0==0 && c<FSS_)
    rsp[((size_t)z*B_ + b)*FSS_ + c] = S[0][lc]+S[1][lc]+S[2][lc]+S[3][lc];
}

// ---------------- final: reward finalize + ns_new assembly ----------------

__global__ __launch_bounds__(256) void k_final(const float* __restrict__ rsp,
                                               const ushort* __restrict__ g,
                                               const float* __restrict__ ns,
                                               float* __restrict__ out) {
  int idx = blockIdx.x*256+threadIdx.x;
  if (idx < OUT_R_) {
    int b = idx / FSS_, c = idx - b*FSS_;
    float s = 0.f;
    #pragma unroll
    for (int z=0;z<8;z++) s += rsp[((size_t)z*B_ + b)*FSS_ + c];
    out[idx] = s;
  } else {
    int j2 = idx - OUT_R_;
    if (j2 >= B_*NSROW_) return;
    int b = j2 / NSROW_; int j = j2 - b*NSROW_;
    float v;
    if (j < SLEFT_) {
      int n = j >> 5, c = j & 31;
      v = b2f(g[(size_t)(b*N_+n)*HLD_ + 640 + c]);
    } else {
      v = ns[(size_t)b*NSROW_ + j];
    }
    out[idx] = v;
  }
}

// ---------------- host driver ----------------

extern "C" void kernel_launch(void* const* d_in, const int* in_sizes, int n_in,
                              void* d_out, int out_size, void* d_ws, size_t ws_size,
                              hipStream_t stream) {
  const float* ns = (const float*)d_in[0];
  const int*   a  = (const int*)d_in[1];

  const float *W[4], *As[4], *Ad[4], *Bb[4], *Sc[3], *Of[3];
  const float *rW[4], *rAs[4], *rAd[4], *rBb[4], *rSc[3], *rOf[3];
  int p = 2;
  for (int i=0;i<4;i++){
    W[i]=(const float*)d_in[p++]; As[i]=(const float*)d_in[p++];
    Ad[i]=(const float*)d_in[p++]; Bb[i]=(const float*)d_in[p++];
    if (i<3){ Sc[i]=(const float*)d_in[p++]; Of[i]=(const float*)d_in[p++]; }
  }
  for (int i=0;i<4;i++){
    rW[i]=(const float*)d_in[p++]; rAs[i]=(const float*)d_in[p++];
    rAd[i]=(const float*)d_in[p++]; rBb[i]=(const float*)d_in[p++];
    if (i<3){ rSc[i]=(const float*)d_in[p++]; rOf[i]=(const float*)d_in[p++]; }
  }

  char* w = (char*)d_ws;
  auto carve = [&](size_t bytes)->void* {
    void* r = (void*)w;
    w += (bytes + 255) & ~(size_t)255;
    return r;
  };
  ushort* xb   = (ushort*)carve((size_t)BN_*736*2);
  ushort* hbuf = (ushort*)carve((size_t)BN_*HLD_*2);
  ushort* gbuf = (ushort*)carve((size_t)BN_*HLD_*2);
  ushort* sabf = (ushort*)carve((size_t)BN_*64*2);
  // zero-region: cnt | fill | esed[4 layers], one memset covers all
  int* cnt     = (int*)carve((size_t)(2*BN_ + 4*4*BN_)*4);
  int* fill    = cnt + BN_;
  float* esedL = (float*)(cnt + 2*BN_);              // 4 x [4*BN]
  float* stp   = (float*)carve((size_t)8*B_*HLD_*4);
  float* rsp   = (float*)carve((size_t)8*B_*FSS_*4);
  int* src_i   = (int*)carve((size_t)BE_*4);
  int* dst_i   = (int*)carve((size_t)BE_*4);
  int* rowptr  = (int*)carve((size_t)(BN_+1)*4);
  int* csr_src = (int*)carve((size_t)BE_*4);
  ushort* Wt[4];
  Wt[0] = (ushort*)carve((size_t)768*64*2);
  Wt[1] = (ushort*)carve((size_t)768*736*2);
  Wt[2] = (ushort*)carve((size_t)768*672*2);
  Wt[3] = (ushort*)carve((size_t)768*672*2);

  float* out = (float*)d_out;

  hipMemsetAsync(cnt, 0, (size_t)(2*BN_ + 16*BN_)*4, stream);

  k_indices<<<(BE_+255)/256, 256, 0, stream>>>(ns, src_i, dst_i, cnt);
  k_scan<<<1, 1024, 0, stream>>>(cnt, rowptr);
  k_scatter<<<(BE_+255)/256, 256, 0, stream>>>(src_i, dst_i, rowptr, fill, csr_src);
  k_sa<<<(BN_*64+255)/256, 256, 0, stream>>>(ns, a, sabf);

  WtP wtp;
  for (int i=0;i<4;i++){ wtp.Wr[i]=rW[i]; wtp.Wn[i]=W[i]; wtp.T[i]=Wt[i]; }
  k_wt_tr<<<1608, 256, 0, stream>>>(wtp);

  dim3 ggrid(6, BN_/64);   // 768 blocks

  const ushort* xin[4] = { sabf, xb, xb, xb };
  int Kp[4]   = { 64, 736, 672, 672 };
  int dns[4]  = { 128, 64, 64, 32 };
  int kRe[4]  = { 64, 608, 608, 608 };   // reward-head K extent
  int kNb[4]  = { 0, 608, 608, 608 };    // next-head K start

  for (int L=0; L<4; ++L) {
    float* esed = esedL + (size_t)L*4*BN_;
    k_gemm<<<ggrid, 256, 0, stream>>>(xin[L], Wt[L], hbuf, esed,
                                      rAs[L], rAd[L], As[L], Ad[L], Kp[L], dns[L],
                                      kRe[L], kNb[L]);
    k_agg<<<BN_/4, 256, 0, stream>>>(hbuf, esed, rowptr, csr_src,
                                     rBb[L], Bb[L], gbuf, dns[L]);
    if (L < 3) {
      k_ln_stats<<<dim3(12, B_, 4), 256, 0, stream>>>(gbuf, stp);
      int Kpn = (L==0) ? 736 : 672;
      k_ln_apply<<<dim3(3, BN_/16), 256, 0, stream>>>(gbuf, stp,
                  rSc[L], rOf[L], Sc[L], Of[L], xb, dns[L], Kpn);
    }
  }

  k_rsum<<<dim3(10, B_, 8), 256, 0, stream>>>(gbuf, rsp);
  k_final<<<(OUT_R_ + B_*NSROW_ + 255)/256, 256, 0, stream>>>(rsp, gbuf, ns, out);
}

// Round 16
// 366.010 us; speedup vs baseline: 3.8261x; 1.0342x over previous
//
#include <hip/hip_runtime.h>
#include <math.h>

#define B_ 16
#define N_ 512
#define D_ 32
#define E_ 8176
#define SLEFT_ 16384
#define FSS_ 601
#define BN_ (B_*N_)            // 8192
#define BE_ (B_*E_)            // 130816
#define NSROW_ (SLEFT_ + 2*E_) // 32736
#define OUT_R_ (B_*FSS_)       // 9616
#define HLD_ 768               // combined width: reward 0..639, next 640..767
#define CAP_ 128               // per-node source bin capacity

typedef __attribute__((ext_vector_type(8))) short short8;
typedef __attribute__((ext_vector_type(4))) float f32x4;

typedef __attribute__((address_space(3))) uint lds_uint;
typedef __attribute__((address_space(1))) const uint g_uint;

__device__ __forceinline__ void gl_lds16(const ushort* gp, ushort* lp) {
  __builtin_amdgcn_global_load_lds((g_uint*)gp, (lds_uint*)lp, 16, 0, 0);
}

__device__ __forceinline__ ushort f2b(float f) {
  uint u = __builtin_bit_cast(uint, f);
  u += 0x7FFFu + ((u >> 16) & 1u);
  return (ushort)(u >> 16);
}
__device__ __forceinline__ float b2f(ushort h) {
  return __builtin_bit_cast(float, ((uint)h) << 16);
}

// ---------------- fused setup: edge-binning | sa | weight transpose -------
// blocks 0..510          : edge binning (no CSR sort; fixed-cap bins)
// blocks 511..2558       : sa build (bf16, K=64 padded)
// blocks 2559..4166      : block-diagonal weight transpose (LDS 32x32 tiles)

struct SetupP {
  const float* ns; const int* a;
  int* cnt; int* bins; ushort* sa;
  const float* Wr[4]; const float* Wn[4]; ushort* T[4];
};

__global__ __launch_bounds__(256) void k_setup(SetupP p) {
  __shared__ float tile[32][33];
  int blk = blockIdx.x;
  if (blk < 511) {
    int idx = blk*256 + threadIdx.x;
    if (idx >= BE_) return;
    int b = idx / E_;
    int j = idx - b*E_;
    const float* row = p.ns + (size_t)b*NSROW_;
    int s = (int)row[SLEFT_ + j];
    int r = (int)row[SLEFT_ + E_ + j];
    int dst = b*N_ + r;
    int pos = atomicAdd(&p.cnt[dst], 1);
    if (pos < CAP_) p.bins[(size_t)dst*CAP_ + pos] = b*N_ + s;
    return;
  }
  if (blk < 2559) {
    int idx = (blk-511)*256 + threadIdx.x;
    int v = idx >> 6, c = idx & 63;
    int b = v >> 9, n = v & 511;
    float val = 0.f;
    if (c < 32)       val = p.ns[(size_t)b*NSROW_ + n*32 + c];
    else if (c == 32) val = (p.a[b]==n) ? 1.f : 0.f;
    p.sa[idx] = f2b(val);
    return;
  }
  int t = blk - 2559;
  int s, base, KP, DINR, DINN, DOUTN, KOFF;
  if (t < 48)        { s=0; base=0;    KP=64;  DINR=33;  DINN=33;  DOUTN=128; KOFF=0;   }
  else if (t < 600)  { s=1; base=48;   KP=736; DINR=601; DINN=128; DOUTN=64;  KOFF=608; }
  else if (t < 1104) { s=2; base=600;  KP=672; DINR=601; DINN=64;  DOUTN=64;  KOFF=608; }
  else               { s=3; base=1104; KP=672; DINR=601; DINN=64;  DOUTN=32;  KOFF=608; }
  int ti = t - base;
  int kt = ti / 24, nt = ti - kt*24;
  int k0 = kt*32, n0 = nt*32;
  int tid = threadIdx.x;
  int cc = tid & 31, rr = tid >> 5;
  #pragma unroll
  for (int it=0; it<4; it++) {
    int k = k0 + it*8 + rr;
    int n = n0 + cc;
    float v = 0.f;
    if (n < 640) { if (n < 601 && k < DINR) v = p.Wr[s][(size_t)k*601 + n]; }
    else { int nn = n-640, kk = k-KOFF;
           if (nn < DOUTN && kk >= 0 && kk < DINN) v = p.Wn[s][(size_t)kk*DOUTN + nn]; }
    tile[it*8+rr][cc] = v;
  }
  __syncthreads();
  #pragma unroll
  for (int it=0; it<4; it++) {
    int n = n0 + it*8 + rr;
    int k = k0 + cc;
    p.T[s][(size_t)n*KP + k] = f2b(tile[cc][it*8+rr]);
  }
}

// ---------------- MFMA bf16 GEMM, 64x128 tile + atomic final es/ed --------
// K-range split: col-blocks 0..4 (reward cols) loop k in [0, kRewEnd);
// col-block 5 (next-head cols) loops k in [kNextBeg, Kpad).

__global__ __launch_bounds__(256) void k_gemm(const ushort* __restrict__ A,
                                              const ushort* __restrict__ Bt,
                                              ushort* __restrict__ C,
                                              float* __restrict__ esed, // es_r|ed_r|es_n|ed_n
                                              const float* __restrict__ asr,
                                              const float* __restrict__ adr,
                                              const float* __restrict__ asn,
                                              const float* __restrict__ adn,
                                              int Kpad, int dn,
                                              int kRewEnd, int kNextBeg) {
  __shared__ ushort Asm[64*32];
  __shared__ ushort Bsm[128*32];
  int tid = threadIdx.x;
  int rowBase = blockIdx.y * 64;
  int colBase = blockIdx.x * 128;
  int kBeg = (blockIdx.x == 5) ? kNextBeg : 0;
  int kEnd = (blockIdx.x == 5) ? Kpad : kRewEnd;
  int wave = tid >> 6, lane = tid & 63;
  int wr = (wave >> 1) * 32, wc = (wave & 1) * 64;
  int lm = lane & 15, lk = (lane >> 4) * 8;

  f32x4 acc[2][4];
  #pragma unroll
  for (int i=0;i<2;i++)
    #pragma unroll
    for (int j=0;j<4;j++) acc[i][j] = (f32x4){0.f,0.f,0.f,0.f};

  int t0 = tid, t1 = tid + 256;
  const ushort* Ag0 = A  + (size_t)(rowBase + (t0>>2))*Kpad + (t0&3)*8;
  const ushort* Bg0 = Bt + (size_t)(colBase + (t0>>2))*Kpad + (t0&3)*8;
  const ushort* Bg1 = Bt + (size_t)(colBase + (t1>>2))*Kpad + (t1&3)*8;
  ushort* Al0 = &Asm[t0*8];
  ushort* Bl0 = &Bsm[t0*8];
  ushort* Bl1 = &Bsm[t1*8];

  for (int k0 = kBeg; k0 < kEnd; k0 += 32) {
    gl_lds16(Ag0 + k0, Al0);
    gl_lds16(Bg0 + k0, Bl0);
    gl_lds16(Bg1 + k0, Bl1);
    __syncthreads();
    short8 af[2], bfr[4];
    #pragma unroll
    for (int i=0;i<2;i++) af[i]  = *(short8*)&Asm[(wr + i*16 + lm)*32 + lk];
    #pragma unroll
    for (int j=0;j<4;j++) bfr[j] = *(short8*)&Bsm[(wc + j*16 + lm)*32 + lk];
    #pragma unroll
    for (int i=0;i<2;i++)
      #pragma unroll
      for (int j=0;j<4;j++)
        acc[i][j] = __builtin_amdgcn_mfma_f32_16x16x32_bf16(af[i], bfr[j], acc[i][j], 0,0,0);
    __syncthreads();
  }

  float asv[4], adv[4];
  #pragma unroll
  for (int j=0;j<4;j++) {
    int col = colBase + wc + j*16 + lm;
    float s = 0.f, d = 0.f;
    if (col < 601)      { s = asr[col];     d = adr[col]; }
    else if (col >= 640 && col - 640 < dn) { s = asn[col-640]; d = adn[col-640]; }
    asv[j] = s; adv[j] = d;
  }
  int cr = lane >> 4;
  int ct2 = blockIdx.x*2 + (wc >> 6);
  float* esp = (ct2 < 10) ? esed : esed + 2*BN_;
  #pragma unroll
  for (int i=0;i<2;i++) {
    #pragma unroll
    for (int j=0;j<4;j++) {
      int col = colBase + wc + j*16 + lm;
      #pragma unroll
      for (int g=0; g<4; g++) {
        int row = rowBase + wr + i*16 + cr*4 + g;
        C[(size_t)row*HLD_ + col] = f2b(acc[i][j][g]);
      }
    }
    #pragma unroll
    for (int g=0; g<4; g++) {
      float se = 0.f, sd = 0.f;
      #pragma unroll
      for (int j=0;j<4;j++) { se += acc[i][j][g]*asv[j]; sd += acc[i][j][g]*adv[j]; }
      #pragma unroll
      for (int o=1;o<16;o<<=1) { se += __shfl_xor(se,o,64); sd += __shfl_xor(sd,o,64); }
      if (lm == 0) {
        int row = rowBase + wr + i*16 + cr*4 + g;
        atomicAdd(&esp[row], se);
        atomicAdd(&esp[BN_ + row], sd);
      }
    }
  }
}

// ---------------- combined softmax + aggregation (one wave per node) ------
// Sources from fixed-cap bins; deg = min(cnt[v], CAP_).

__global__ __launch_bounds__(256) void k_agg(const ushort* __restrict__ h,
                                             const float* __restrict__ esed,
                                             const int* __restrict__ cnt,
                                             const int* __restrict__ bins,
                                             const float* __restrict__ bias_r,
                                             const float* __restrict__ bias_n,
                                             ushort* __restrict__ g,
                                             int dn) {
  const float* es_r = esed;
  const float* ed_r = esed + BN_;
  const float* es_n = esed + 2*BN_;
  const float* ed_n = esed + 3*BN_;
  int wid = threadIdx.x>>6, lane = threadIdx.x&63;
  int bid = blockIdx.x;
  int xcd = bid & 7, slot = bid >> 3;
  int graph = xcd + ((slot >> 7) << 3);
  int v = graph*512 + (slot & 127)*4 + wid;
  int s0 = v * CAP_;
  int deg = cnt[v]; if (deg > CAP_) deg = CAP_;
  float edr = ed_r[v], edn = ed_n[v];

  int ch0 = lane, ch1 = lane + 64;
  bool a1 = ch1 < 96;
  bool c1r = ch1 < 80;
  float acc0[8], acc1[8];
  #pragma unroll
  for (int q=0;q<8;q++){ acc0[q]=0.f; acc1[q]=0.f; }

  if (deg <= 64) {
    bool has = lane < deg;
    int u = 0; float er = -__builtin_inff(), en = -__builtin_inff();
    if (has) {
      u = bins[s0 + lane];
      er = es_r[u] + edr; er = er > 0.f ? er : 0.2f*er;
      en = es_n[u] + edn; en = en > 0.f ? en : 0.2f*en;
    }
    float mr = er, mn = en;
    #pragma unroll
    for (int o=32;o;o>>=1) { mr = fmaxf(mr, __shfl_xor(mr,o,64)); mn = fmaxf(mn, __shfl_xor(mn,o,64)); }
    float pr = has ? __expf(er - mr) : 0.f;
    float pn = has ? __expf(en - mn) : 0.f;
    float dr = pr, dnm = pn;
    #pragma unroll
    for (int o=32;o;o>>=1) { dr += __shfl_xor(dr,o,64); dnm += __shfl_xor(dnm,o,64); }
    pr *= 1.f/(dr + 1e-16f);
    pn *= 1.f/(dnm + 1e-16f);

    for (int t0 = 0; t0 < deg; t0 += 4) {
      int nt = deg - t0; if (nt > 4) nt = 4;
      short8 va[4], vb[4];
      float w0[4], w1[4];
      #pragma unroll
      for (int q=0;q<4;q++) {
        if (q < nt) {
          int uu = __shfl(u, t0+q, 64);
          w0[q] = __shfl(pr, t0+q, 64);
          w1[q] = __shfl(pn, t0+q, 64);
          const ushort* hp = h + (size_t)uu*HLD_;
          va[q] = *(const short8*)&hp[ch0*8];
          vb[q] = a1 ? *(const short8*)&hp[ch1*8] : short8{};
        } else {
          w0[q] = 0.f; w1[q] = 0.f; va[q] = short8{}; vb[q] = short8{};
        }
      }
      #pragma unroll
      for (int q=0;q<4;q++) {
        #pragma unroll
        for (int r=0;r<8;r++) acc0[r] += w0[q] * b2f((ushort)va[q][r]);
        if (a1) {
          float wv = c1r ? w0[q] : w1[q];
          #pragma unroll
          for (int r=0;r<8;r++) acc1[r] += wv * b2f((ushort)vb[q][r]);
        }
      }
    }
  } else {
    int e0 = s0 + deg;
    float mr = -__builtin_inff(), mn = -__builtin_inff();
    for (int j = s0 + lane; j < e0; j += 64) {
      int u = bins[j];
      float er = es_r[u] + edr; er = er>0.f?er:0.2f*er;
      float en = es_n[u] + edn; en = en>0.f?en:0.2f*en;
      mr = fmaxf(mr, er); mn = fmaxf(mn, en);
    }
    #pragma unroll
    for (int o=32;o;o>>=1) { mr=fmaxf(mr,__shfl_xor(mr,o,64)); mn=fmaxf(mn,__shfl_xor(mn,o,64)); }
    float dr=0.f, dnm=0.f;
    for (int j = s0 + lane; j < e0; j += 64) {
      int u = bins[j];
      float er = es_r[u] + edr; er = er>0.f?er:0.2f*er;
      float en = es_n[u] + edn; en = en>0.f?en:0.2f*en;
      dr += __expf(er-mr); dnm += __expf(en-mn);
    }
    #pragma unroll
    for (int o=32;o;o>>=1) { dr+=__shfl_xor(dr,o,64); dnm+=__shfl_xor(dnm,o,64); }
    float ir = 1.f/(dr+1e-16f), in_ = 1.f/(dnm+1e-16f);
    for (int j = s0; j < e0; ++j) {
      int uu = bins[j];
      float er = es_r[uu] + edr; er = er>0.f?er:0.2f*er;
      float en = es_n[uu] + edn; en = en>0.f?en:0.2f*en;
      float wr2 = __expf(er-mr)*ir, wn2 = __expf(en-mn)*in_;
      const ushort* hp = h + (size_t)uu*HLD_;
      short8 hv = *(const short8*)&hp[ch0*8];
      #pragma unroll
      for (int q=0;q<8;q++) acc0[q] += wr2 * b2f((ushort)hv[q]);
      if (a1) {
        short8 hv2 = *(const short8*)&hp[ch1*8];
        float wv = c1r ? wr2 : wn2;
        #pragma unroll
        for (int q=0;q<8;q++) acc1[q] += wv * b2f((ushort)hv2[q]);
      }
    }
  }

  ushort* gv = g + (size_t)v*HLD_;
  {
    int cb = ch0*8;
    short8 ov;
    #pragma unroll
    for (int q=0;q<8;q++) ov[q] = (short)f2b(acc0[q] + bias_r[cb+q]);
    *(short8*)&gv[cb] = ov;
  }
  if (a1) {
    int cb = ch1*8;
    short8 ov;
    #pragma unroll
    for (int q=0;q<8;q++) {
      int c = cb+q;
      float val;
      if (c < 601)                         val = acc1[q] + bias_r[c];
      else if (c >= 640 && (c-640) < dn)   val = acc1[q] + bias_n[c-640];
      else                                 val = 0.f;
      ov[q] = (short)f2b(val);
    }
    *(short8*)&gv[cb] = ov;
  }
}

// ---------------- LN stats partials (z=4 chunks of 128 rows) --------------

__global__ __launch_bounds__(256) void k_ln_stats(const ushort* __restrict__ g,
                                                  float* __restrict__ st) {
  int b = blockIdx.y, z = blockIdx.z; int n0 = z*128;
  int lc = threadIdx.x & 63, r0 = threadIdx.x >> 6;
  int c = blockIdx.x*64 + lc;
  float s=0.f, q=0.f;
  #pragma unroll 4
  for (int i=0;i<32;i++) {
    int n = n0 + r0*32 + i;
    float x = b2f(g[(size_t)(b*N_+n)*HLD_ + c]);
    s+=x; q+=x*x;
  }
  __shared__ float S[4][64], Q[4][64];
  S[r0][lc]=s; Q[r0][lc]=q; __syncthreads();
  if (r0==0) {
    st[((size_t)(z*2+0)*B_ + b)*HLD_ + c] = S[0][lc]+S[1][lc]+S[2][lc]+S[3][lc];
    st[((size_t)(z*2+1)*B_ + b)*HLD_ + c] = Q[0][lc]+Q[1][lc]+Q[2][lc]+Q[3][lc];
  }
}

// ---------------- LN apply + ReLU (finalize folded; col pair x 16 rows) ---

__global__ __launch_bounds__(256) void k_ln_apply(const ushort* __restrict__ g,
                                                  const float* __restrict__ st,
                                                  const float* __restrict__ scr,
                                                  const float* __restrict__ ofr,
                                                  const float* __restrict__ scn,
                                                  const float* __restrict__ ofn,
                                                  ushort* __restrict__ xb,
                                                  int dn, int Kpad) {
  int tid = threadIdx.x;
  int pp = blockIdx.x*128 + (tid & 127);
  int c0 = pp*2;
  if (c0 >= Kpad) return;
  int vbase = blockIdx.y*16;
  int b = vbase >> 9;
  float mv[2], av[2];
  #pragma unroll
  for (int q=0;q<2;q++) {
    int c = c0+q;
    int cs; bool valid; float scale, offs;
    if (c < 608) { cs = c; valid = c < 601;
                   scale = valid ? scr[c] : 0.f; offs = valid ? ofr[c] : 0.f; }
    else { int cn = c - 608; cs = 640 + cn; valid = cn < dn;
           scale = valid ? scn[cn] : 0.f; offs = valid ? ofn[cn] : 0.f; }
    float mul = 0.f, add = 0.f;
    if (valid) {
      float s=0.f, qq=0.f;
      #pragma unroll
      for (int z=0;z<4;z++) {
        s  += st[((size_t)(z*2+0)*B_ + b)*HLD_ + cs];
        qq += st[((size_t)(z*2+1)*B_ + b)*HLD_ + cs];
      }
      float mu = s*(1.f/N_);
      float var = qq*(1.f/N_) - mu*mu;
      float rs = rsqrtf(var+1e-5f);
      mul = rs*scale;
      add = offs - mu*rs*scale;
    }
    mv[q] = mul; av[q] = add;
  }
  int cs0 = (c0 < 608) ? c0 : 640 + (c0 - 608);
  for (int i = tid >> 7; i < 16; i += 2) {
    int v = vbase + i;
    uint gg = *(const uint*)&g[(size_t)v*HLD_ + cs0];
    float x0 = b2f((ushort)(gg & 0xFFFFu));
    float x1 = b2f((ushort)(gg >> 16));
    float y0 = x0*mv[0] + av[0]; y0 = y0 > 0.f ? y0 : 0.f;
    float y1 = x1*mv[1] + av[1]; y1 = y1 > 0.f ? y1 : 0.f;
    *(uint*)&xb[(size_t)v*Kpad + c0] = ((uint)f2b(y1) << 16) | f2b(y0);
  }
}

// ---------------- reward: sum over nodes (slot partials) ----------------

__global__ __launch_bounds__(256) void k_rsum(const ushort* __restrict__ g,
                                              float* __restrict__ rsp) {
  int b = blockIdx.y, z = blockIdx.z; int n0 = z*64;
  int lc = threadIdx.x & 63, r0 = threadIdx.x>>6;
  int c = blockIdx.x*64 + lc;
  float s = 0.f;
  if (c < FSS_) {
    #pragma unroll 4
    for (int i=0;i<16;i++) {
      int n = n0 + r0*16 + i;
      s += b2f(g[(size_t)(b*N_+n)*HLD_ + c]);
    }
  }
  __shared__ float S[4][64];
  S[r0][lc]=s; __syncthreads();
  if (r0==0 && c<FSS_)
    rsp[((size_t)z*B_ + b)*FSS_ + c] = S[0][lc]+S[1][lc]+S[2][lc]+S[3][lc];
}

// ---------------- final: reward finalize + ns_new assembly ----------------

__global__ __launch_bounds__(256) void k_final(const float* __restrict__ rsp,
                                               const ushort* __restrict__ g,
                                               const float* __restrict__ ns,
                                               float* __restrict__ out) {
  int idx = blockIdx.x*256+threadIdx.x;
  if (idx < OUT_R_) {
    int b = idx / FSS_, c = idx - b*FSS_;
    float s = 0.f;
    #pragma unroll
    for (int z=0;z<8;z++) s += rsp[((size_t)z*B_ + b)*FSS_ + c];
    out[idx] = s;
  } else {
    int j2 = idx - OUT_R_;
    if (j2 >= B_*NSROW_) return;
    int b = j2 / NSROW_; int j = j2 - b*NSROW_;
    float v;
    if (j < SLEFT_) {
      int n = j >> 5, c = j & 31;
      v = b2f(g[(size_t)(b*N_+n)*HLD_ + 640 + c]);
    } else {
      v = ns[(size_t)b*NSROW_ + j];
    }
    out[idx] = v;
  }
}

// ---------------- host driver ----------------

extern "C" void kernel_launch(void* const* d_in, const int* in_sizes, int n_in,
                              void* d_out, int out_size, void* d_ws, size_t ws_size,
                              hipStream_t stream) {
  const float* ns = (const float*)d_in[0];
  const int*   a  = (const int*)d_in[1];

  const float *W[4], *As[4], *Ad[4], *Bb[4], *Sc[3], *Of[3];
  const float *rW[4], *rAs[4], *rAd[4], *rBb[4], *rSc[3], *rOf[3];
  int p = 2;
  for (int i=0;i<4;i++){
    W[i]=(const float*)d_in[p++]; As[i]=(const float*)d_in[p++];
    Ad[i]=(const float*)d_in[p++]; Bb[i]=(const float*)d_in[p++];
    if (i<3){ Sc[i]=(const float*)d_in[p++]; Of[i]=(const float*)d_in[p++]; }
  }
  for (int i=0;i<4;i++){
    rW[i]=(const float*)d_in[p++]; rAs[i]=(const float*)d_in[p++];
    rAd[i]=(const float*)d_in[p++]; rBb[i]=(const float*)d_in[p++];
    if (i<3){ rSc[i]=(const float*)d_in[p++]; rOf[i]=(const float*)d_in[p++]; }
  }

  char* w = (char*)d_ws;
  auto carve = [&](size_t bytes)->void* {
    void* r = (void*)w;
    w += (bytes + 255) & ~(size_t)255;
    return r;
  };
  ushort* xb   = (ushort*)carve((size_t)BN_*736*2);
  ushort* hbuf = (ushort*)carve((size_t)BN_*HLD_*2);
  ushort* gbuf = (ushort*)carve((size_t)BN_*HLD_*2);
  ushort* sabf = (ushort*)carve((size_t)BN_*64*2);
  // zero-region: cnt | esed[4 layers] — one memset covers all
  int* cnt     = (int*)carve((size_t)(BN_ + 4*4*BN_)*4);
  float* esedL = (float*)(cnt + BN_);                // 4 x [4*BN]
  int* bins    = (int*)carve((size_t)BN_*CAP_*4);    // 4 MB
  float* stp   = (float*)carve((size_t)8*B_*HLD_*4);
  float* rsp   = (float*)carve((size_t)8*B_*FSS_*4);
  ushort* Wt[4];
  Wt[0] = (ushort*)carve((size_t)768*64*2);
  Wt[1] = (ushort*)carve((size_t)768*736*2);
  Wt[2] = (ushort*)carve((size_t)768*672*2);
  Wt[3] = (ushort*)carve((size_t)768*672*2);

  float* out = (float*)d_out;

  hipMemsetAsync(cnt, 0, (size_t)(BN_ + 16*BN_)*4, stream);

  SetupP sp;
  sp.ns = ns; sp.a = a; sp.cnt = cnt; sp.bins = bins; sp.sa = sabf;
  for (int i=0;i<4;i++){ sp.Wr[i]=rW[i]; sp.Wn[i]=W[i]; sp.T[i]=Wt[i]; }
  k_setup<<<4167, 256, 0, stream>>>(sp);

  dim3 ggrid(6, BN_/64);   // 768 blocks

  const ushort* xin[4] = { sabf, xb, xb, xb };
  int Kp[4]   = { 64, 736, 672, 672 };
  int dns[4]  = { 128, 64, 64, 32 };
  int kRe[4]  = { 64, 608, 608, 608 };   // reward-head K extent
  int kNb[4]  = { 0, 608, 608, 608 };    // next-head K start

  for (int L=0; L<4; ++L) {
    float* esed = esedL + (size_t)L*4*BN_;
    k_gemm<<<ggrid, 256, 0, stream>>>(xin[L], Wt[L], hbuf, esed,
                                      rAs[L], rAd[L], As[L], Ad[L], Kp[L], dns[L],
                                      kRe[L], kNb[L]);
    k_agg<<<BN_/4, 256, 0, stream>>>(hbuf, esed, cnt, bins,
                                     rBb[L], Bb[L], gbuf, dns[L]);
    if (L < 3) {
      k_ln_stats<<<dim3(12, B_, 4), 256, 0, stream>>>(gbuf, stp);
      int Kpn = (L==0) ? 736 : 672;
      k_ln_apply<<<dim3(3, BN_/16), 256, 0, stream>>>(gbuf, stp,
                  rSc[L], rOf[L], Sc[L], Of[L], xb, dns[L], Kpn);
    }
  }

  k_rsum<<<dim3(10, B_, 8), 256, 0, stream>>>(gbuf, rsp);
  k_final<<<(OUT_R_ + B_*NSROW_ + 255)/256, 256, 0, stream>>>(rsp, gbuf, ns, out);
}

// Round 17
// 351.799 us; speedup vs baseline: 3.9807x; 1.0404x over previous
//
#include <hip/hip_runtime.h>
#include <math.h>

#define B_ 16
#define N_ 512
#define D_ 32
#define E_ 8176
#define SLEFT_ 16384
#define FSS_ 601
#define BN_ (B_*N_)            // 8192
#define BE_ (B_*E_)            // 130816
#define NSROW_ (SLEFT_ + 2*E_) // 32736
#define OUT_R_ (B_*FSS_)       // 9616
#define HLD_ 768               // combined width: reward 0..639, next 640..767
#define CAP_ 128               // per-node source bin capacity
#define KXB_ 736               // max xb-space K width

typedef __attribute__((ext_vector_type(8))) short short8;
typedef __attribute__((ext_vector_type(4))) float f32x4;

typedef __attribute__((address_space(3))) uint lds_uint;
typedef __attribute__((address_space(1))) const uint g_uint;

__device__ __forceinline__ void gl_lds16(const ushort* gp, ushort* lp) {
  __builtin_amdgcn_global_load_lds((g_uint*)gp, (lds_uint*)lp, 16, 0, 0);
}

__device__ __forceinline__ ushort f2b(float f) {
  uint u = __builtin_bit_cast(uint, f);
  u += 0x7FFFu + ((u >> 16) & 1u);
  return (ushort)(u >> 16);
}
__device__ __forceinline__ float b2f(ushort h) {
  return __builtin_bit_cast(float, ((uint)h) << 16);
}

// ---------------- fused setup: edge-binning | sa | weight transpose -------

struct SetupP {
  const float* ns; const int* a;
  int* cnt; int* bins; ushort* sa;
  const float* Wr[4]; const float* Wn[4]; ushort* T[4];
};

__global__ __launch_bounds__(256) void k_setup(SetupP p) {
  __shared__ float tile[32][33];
  int blk = blockIdx.x;
  if (blk < 511) {
    int idx = blk*256 + threadIdx.x;
    if (idx >= BE_) return;
    int b = idx / E_;
    int j = idx - b*E_;
    const float* row = p.ns + (size_t)b*NSROW_;
    int s = (int)row[SLEFT_ + j];
    int r = (int)row[SLEFT_ + E_ + j];
    int dst = b*N_ + r;
    int pos = atomicAdd(&p.cnt[dst], 1);
    if (pos < CAP_) p.bins[(size_t)dst*CAP_ + pos] = b*N_ + s;
    return;
  }
  if (blk < 2559) {
    int idx = (blk-511)*256 + threadIdx.x;
    int v = idx >> 6, c = idx & 63;
    int b = v >> 9, n = v & 511;
    float val = 0.f;
    if (c < 32)       val = p.ns[(size_t)b*NSROW_ + n*32 + c];
    else if (c == 32) val = (p.a[b]==n) ? 1.f : 0.f;
    p.sa[idx] = f2b(val);
    return;
  }
  int t = blk - 2559;
  int s, base, KP, DINR, DINN, DOUTN, KOFF;
  if (t < 48)        { s=0; base=0;    KP=64;  DINR=33;  DINN=33;  DOUTN=128; KOFF=0;   }
  else if (t < 600)  { s=1; base=48;   KP=736; DINR=601; DINN=128; DOUTN=64;  KOFF=608; }
  else if (t < 1104) { s=2; base=600;  KP=672; DINR=601; DINN=64;  DOUTN=64;  KOFF=608; }
  else               { s=3; base=1104; KP=672; DINR=601; DINN=64;  DOUTN=32;  KOFF=608; }
  int ti = t - base;
  int kt = ti / 24, nt = ti - kt*24;
  int k0 = kt*32, n0 = nt*32;
  int tid = threadIdx.x;
  int cc = tid & 31, rr = tid >> 5;
  #pragma unroll
  for (int it=0; it<4; it++) {
    int k = k0 + it*8 + rr;
    int n = n0 + cc;
    float v = 0.f;
    if (n < 640) { if (n < 601 && k < DINR) v = p.Wr[s][(size_t)k*601 + n]; }
    else { int nn = n-640, kk = k-KOFF;
           if (nn < DOUTN && kk >= 0 && kk < DINN) v = p.Wn[s][(size_t)kk*DOUTN + nn]; }
    tile[it*8+rr][cc] = v;
  }
  __syncthreads();
  #pragma unroll
  for (int it=0; it<4; it++) {
    int n = n0 + it*8 + rr;
    int k = k0 + cc;
    p.T[s][(size_t)n*KP + k] = f2b(tile[cc][it*8+rr]);
  }
}

// ---------------- MFMA bf16 GEMM, 64x128 tile + atomic final es/ed --------
// useLN: A sourced from g (768-wide), LN relu(x*mul+add) applied during
// VGPR->LDS staging; col-block 5's K-range maps to g cols k+32.
// Otherwise: A staged via gl_lds16 unchanged.

__global__ __launch_bounds__(256) void k_gemm(const ushort* __restrict__ A,
                                              const ushort* __restrict__ Bt,
                                              ushort* __restrict__ C,
                                              float* __restrict__ esed, // es_r|ed_r|es_n|ed_n
                                              const float* __restrict__ asr,
                                              const float* __restrict__ adr,
                                              const float* __restrict__ asn,
                                              const float* __restrict__ adn,
                                              const float* __restrict__ mulb,
                                              const float* __restrict__ addb,
                                              int Kpad, int dn,
                                              int kRewEnd, int kNextBeg, int useLN) {
  __shared__ ushort Asm[64*32];
  __shared__ ushort Bsm[128*32];
  __shared__ float Lm[KXB_], La[KXB_];
  int tid = threadIdx.x;
  int rowBase = blockIdx.y * 64;
  int colBase = blockIdx.x * 128;
  int kBeg = (blockIdx.x == 5) ? kNextBeg : 0;
  int kEnd = (blockIdx.x == 5) ? Kpad : kRewEnd;
  int wave = tid >> 6, lane = tid & 63;
  int wr = (wave >> 1) * 32, wc = (wave & 1) * 64;
  int lm = lane & 15, lk = (lane >> 4) * 8;

  f32x4 acc[2][4];
  #pragma unroll
  for (int i=0;i<2;i++)
    #pragma unroll
    for (int j=0;j<4;j++) acc[i][j] = (f32x4){0.f,0.f,0.f,0.f};

  int t0 = tid, t1 = tid + 256;
  int ar = t0 >> 2, ac8 = (t0 & 3) * 8;
  const ushort* Bg0 = Bt + (size_t)(colBase + (t0>>2))*Kpad + (t0&3)*8;
  const ushort* Bg1 = Bt + (size_t)(colBase + (t1>>2))*Kpad + (t1&3)*8;
  ushort* Bl0 = &Bsm[t0*8];
  ushort* Bl1 = &Bsm[t1*8];
  ushort* Al0 = &Asm[t0*8];

  const ushort* Ag_lds = A + (size_t)(rowBase + ar)*Kpad + ac8;   // !useLN path
  int koff = (blockIdx.x == 5) ? 32 : 0;
  const ushort* Ag_vg  = A + (size_t)(rowBase + ar)*HLD_ + koff;  // useLN path

  if (useLN) {
    int b = rowBase >> 9;
    for (int i = tid; i < KXB_; i += 256) {
      Lm[i] = mulb[(size_t)b*KXB_ + i];
      La[i] = addb[(size_t)b*KXB_ + i];
    }
    __syncthreads();
  }

  for (int k0 = kBeg; k0 < kEnd; k0 += 32) {
    gl_lds16(Bg0 + k0, Bl0);
    gl_lds16(Bg1 + k0, Bl1);
    if (useLN) {
      short8 av = *(const short8*)&Ag_vg[k0 + ac8];
      short8 ov;
      #pragma unroll
      for (int q=0;q<8;q++) {
        float x = b2f((ushort)av[q]);
        float y = x * Lm[k0 + ac8 + q] + La[k0 + ac8 + q];
        y = y > 0.f ? y : 0.f;
        ov[q] = (short)f2b(y);
      }
      *(short8*)Al0 = ov;
    } else {
      gl_lds16(Ag_lds + k0, Al0);
    }
    __syncthreads();
    short8 af[2], bfr[4];
    #pragma unroll
    for (int i=0;i<2;i++) af[i]  = *(short8*)&Asm[(wr + i*16 + lm)*32 + lk];
    #pragma unroll
    for (int j=0;j<4;j++) bfr[j] = *(short8*)&Bsm[(wc + j*16 + lm)*32 + lk];
    #pragma unroll
    for (int i=0;i<2;i++)
      #pragma unroll
      for (int j=0;j<4;j++)
        acc[i][j] = __builtin_amdgcn_mfma_f32_16x16x32_bf16(af[i], bfr[j], acc[i][j], 0,0,0);
    __syncthreads();
  }

  float asv[4], adv[4];
  #pragma unroll
  for (int j=0;j<4;j++) {
    int col = colBase + wc + j*16 + lm;
    float s = 0.f, d = 0.f;
    if (col < 601)      { s = asr[col];     d = adr[col]; }
    else if (col >= 640 && col - 640 < dn) { s = asn[col-640]; d = adn[col-640]; }
    asv[j] = s; adv[j] = d;
  }
  int cr = lane >> 4;
  int ct2 = blockIdx.x*2 + (wc >> 6);
  float* esp = (ct2 < 10) ? esed : esed + 2*BN_;
  #pragma unroll
  for (int i=0;i<2;i++) {
    #pragma unroll
    for (int j=0;j<4;j++) {
      int col = colBase + wc + j*16 + lm;
      #pragma unroll
      for (int g=0; g<4; g++) {
        int row = rowBase + wr + i*16 + cr*4 + g;
        C[(size_t)row*HLD_ + col] = f2b(acc[i][j][g]);
      }
    }
    #pragma unroll
    for (int g=0; g<4; g++) {
      float se = 0.f, sd = 0.f;
      #pragma unroll
      for (int j=0;j<4;j++) { se += acc[i][j][g]*asv[j]; sd += acc[i][j][g]*adv[j]; }
      #pragma unroll
      for (int o=1;o<16;o<<=1) { se += __shfl_xor(se,o,64); sd += __shfl_xor(sd,o,64); }
      if (lm == 0) {
        int row = rowBase + wr + i*16 + cr*4 + g;
        atomicAdd(&esp[row], se);
        atomicAdd(&esp[BN_ + row], sd);
      }
    }
  }
}

// ---------------- combined softmax + aggregation (one wave per node) ------

__global__ __launch_bounds__(256) void k_agg(const ushort* __restrict__ h,
                                             const float* __restrict__ esed,
                                             const int* __restrict__ cnt,
                                             const int* __restrict__ bins,
                                             const float* __restrict__ bias_r,
                                             const float* __restrict__ bias_n,
                                             ushort* __restrict__ g,
                                             int dn) {
  const float* es_r = esed;
  const float* ed_r = esed + BN_;
  const float* es_n = esed + 2*BN_;
  const float* ed_n = esed + 3*BN_;
  int wid = threadIdx.x>>6, lane = threadIdx.x&63;
  int bid = blockIdx.x;
  int xcd = bid & 7, slot = bid >> 3;
  int graph = xcd + ((slot >> 7) << 3);
  int v = graph*512 + (slot & 127)*4 + wid;
  int s0 = v * CAP_;
  int deg = cnt[v]; if (deg > CAP_) deg = CAP_;
  float edr = ed_r[v], edn = ed_n[v];

  int nch = (640 + dn + 7) >> 3;   // 96 / 88 / 84 real 8-col chunks
  int ch0 = lane, ch1 = lane + 64;
  bool a1 = ch1 < nch;
  bool c1r = ch1 < 80;
  float acc0[8], acc1[8];
  #pragma unroll
  for (int q=0;q<8;q++){ acc0[q]=0.f; acc1[q]=0.f; }

  if (deg <= 64) {
    bool has = lane < deg;
    int u = 0; float er = -__builtin_inff(), en = -__builtin_inff();
    if (has) {
      u = bins[s0 + lane];
      er = es_r[u] + edr; er = er > 0.f ? er : 0.2f*er;
      en = es_n[u] + edn; en = en > 0.f ? en : 0.2f*en;
    }
    float mr = er, mn = en;
    #pragma unroll
    for (int o=32;o;o>>=1) { mr = fmaxf(mr, __shfl_xor(mr,o,64)); mn = fmaxf(mn, __shfl_xor(mn,o,64)); }
    float pr = has ? __expf(er - mr) : 0.f;
    float pn = has ? __expf(en - mn) : 0.f;
    float dr = pr, dnm = pn;
    #pragma unroll
    for (int o=32;o;o>>=1) { dr += __shfl_xor(dr,o,64); dnm += __shfl_xor(dnm,o,64); }
    pr *= 1.f/(dr + 1e-16f);
    pn *= 1.f/(dnm + 1e-16f);

    for (int t0 = 0; t0 < deg; t0 += 4) {
      int nt = deg - t0; if (nt > 4) nt = 4;
      short8 va[4], vb[4];
      float w0[4], w1[4];
      #pragma unroll
      for (int q=0;q<4;q++) {
        if (q < nt) {
          int uu = __shfl(u, t0+q, 64);
          w0[q] = __shfl(pr, t0+q, 64);
          w1[q] = __shfl(pn, t0+q, 64);
          const ushort* hp = h + (size_t)uu*HLD_;
          va[q] = *(const short8*)&hp[ch0*8];
          vb[q] = a1 ? *(const short8*)&hp[ch1*8] : short8{};
        } else {
          w0[q] = 0.f; w1[q] = 0.f; va[q] = short8{}; vb[q] = short8{};
        }
      }
      #pragma unroll
      for (int q=0;q<4;q++) {
        #pragma unroll
        for (int r=0;r<8;r++) acc0[r] += w0[q] * b2f((ushort)va[q][r]);
        if (a1) {
          float wv = c1r ? w0[q] : w1[q];
          #pragma unroll
          for (int r=0;r<8;r++) acc1[r] += wv * b2f((ushort)vb[q][r]);
        }
      }
    }
  } else {
    int e0 = s0 + deg;
    float mr = -__builtin_inff(), mn = -__builtin_inff();
    for (int j = s0 + lane; j < e0; j += 64) {
      int u = bins[j];
      float er = es_r[u] + edr; er = er>0.f?er:0.2f*er;
      float en = es_n[u] + edn; en = en>0.f?en:0.2f*en;
      mr = fmaxf(mr, er); mn = fmaxf(mn, en);
    }
    #pragma unroll
    for (int o=32;o;o>>=1) { mr=fmaxf(mr,__shfl_xor(mr,o,64)); mn=fmaxf(mn,__shfl_xor(mn,o,64)); }
    float dr=0.f, dnm=0.f;
    for (int j = s0 + lane; j < e0; j += 64) {
      int u = bins[j];
      float er = es_r[u] + edr; er = er>0.f?er:0.2f*er;
      float en = es_n[u] + edn; en = en>0.f?en:0.2f*en;
      dr += __expf(er-mr); dnm += __expf(en-mn);
    }
    #pragma unroll
    for (int o=32;o;o>>=1) { dr+=__shfl_xor(dr,o,64); dnm+=__shfl_xor(dnm,o,64); }
    float ir = 1.f/(dr+1e-16f), in_ = 1.f/(dnm+1e-16f);
    for (int j = s0; j < e0; ++j) {
      int uu = bins[j];
      float er = es_r[uu] + edr; er = er>0.f?er:0.2f*er;
      float en = es_n[uu] + edn; en = en>0.f?en:0.2f*en;
      float wr2 = __expf(er-mr)*ir, wn2 = __expf(en-mn)*in_;
      const ushort* hp = h + (size_t)uu*HLD_;
      short8 hv = *(const short8*)&hp[ch0*8];
      #pragma unroll
      for (int q=0;q<8;q++) acc0[q] += wr2 * b2f((ushort)hv[q]);
      if (a1) {
        short8 hv2 = *(const short8*)&hp[ch1*8];
        float wv = c1r ? wr2 : wn2;
        #pragma unroll
        for (int q=0;q<8;q++) acc1[q] += wv * b2f((ushort)hv2[q]);
      }
    }
  }

  ushort* gv = g + (size_t)v*HLD_;
  {
    int cb = ch0*8;
    short8 ov;
    #pragma unroll
    for (int q=0;q<8;q++) ov[q] = (short)f2b(acc0[q] + bias_r[cb+q]);
    *(short8*)&gv[cb] = ov;
  }
  if (a1) {
    int cb = ch1*8;
    short8 ov;
    #pragma unroll
    for (int q=0;q<8;q++) {
      int c = cb+q;
      float val;
      if (c < 601)                         val = acc1[q] + bias_r[c];
      else if (c >= 640 && (c-640) < dn)   val = acc1[q] + bias_n[c-640];
      else                                 val = 0.f;
      ov[q] = (short)f2b(val);
    }
    *(short8*)&gv[cb] = ov;
  }
}

// ---------------- LN stats partials (z=4 chunks of 128 rows) --------------

__global__ __launch_bounds__(256) void k_ln_stats(const ushort* __restrict__ g,
                                                  float* __restrict__ st) {
  int b = blockIdx.y, z = blockIdx.z; int n0 = z*128;
  int lc = threadIdx.x & 63, r0 = threadIdx.x >> 6;
  int c = blockIdx.x*64 + lc;
  float s=0.f, q=0.f;
  #pragma unroll 4
  for (int i=0;i<32;i++) {
    int n = n0 + r0*32 + i;
    float x = b2f(g[(size_t)(b*N_+n)*HLD_ + c]);
    s+=x; q+=x*x;
  }
  __shared__ float S[4][64], Q[4][64];
  S[r0][lc]=s; Q[r0][lc]=q; __syncthreads();
  if (r0==0) {
    st[((size_t)(z*2+0)*B_ + b)*HLD_ + c] = S[0][lc]+S[1][lc]+S[2][lc]+S[3][lc];
    st[((size_t)(z*2+1)*B_ + b)*HLD_ + c] = Q[0][lc]+Q[1][lc]+Q[2][lc]+Q[3][lc];
  }
}

// ---------------- LN finalize: mul/add per (graph, xb col) ----------------

__global__ __launch_bounds__(256) void k_stfin(const float* __restrict__ st,
                                               const float* __restrict__ scr,
                                               const float* __restrict__ ofr,
                                               const float* __restrict__ scn,
                                               const float* __restrict__ ofn,
                                               float* __restrict__ mulb,
                                               float* __restrict__ addb,
                                               int dn) {
  int c = blockIdx.x*256 + threadIdx.x;
  int b = blockIdx.y;
  if (c >= KXB_) return;
  int cs; bool valid; float scale, offs;
  if (c < 608) { cs = c; valid = c < 601;
                 scale = valid ? scr[c] : 0.f; offs = valid ? ofr[c] : 0.f; }
  else { int cn = c - 608; cs = 640 + cn; valid = cn < dn;
         scale = valid ? scn[cn] : 0.f; offs = valid ? ofn[cn] : 0.f; }
  float mul = 0.f, add = 0.f;
  if (valid) {
    float s=0.f, qq=0.f;
    #pragma unroll
    for (int z=0;z<4;z++) {
      s  += st[((size_t)(z*2+0)*B_ + b)*HLD_ + cs];
      qq += st[((size_t)(z*2+1)*B_ + b)*HLD_ + cs];
    }
    float mu = s*(1.f/N_);
    float var = qq*(1.f/N_) - mu*mu;
    float rs = rsqrtf(var+1e-5f);
    mul = rs*scale;
    add = offs - mu*rs*scale;
  }
  mulb[(size_t)b*KXB_ + c] = mul;
  addb[(size_t)b*KXB_ + c] = add;
}

// ---------------- reward: sum over nodes (slot partials) ----------------

__global__ __launch_bounds__(256) void k_rsum(const ushort* __restrict__ g,
                                              float* __restrict__ rsp) {
  int b = blockIdx.y, z = blockIdx.z; int n0 = z*64;
  int lc = threadIdx.x & 63, r0 = threadIdx.x>>6;
  int c = blockIdx.x*64 + lc;
  float s = 0.f;
  if (c < FSS_) {
    #pragma unroll 4
    for (int i=0;i<16;i++) {
      int n = n0 + r0*16 + i;
      s += b2f(g[(size_t)(b*N_+n)*HLD_ + c]);
    }
  }
  __shared__ float S[4][64];
  S[r0][lc]=s; __syncthreads();
  if (r0==0 && c<FSS_)
    rsp[((size_t)z*B_ + b)*FSS_ + c] = S[0][lc]+S[1][lc]+S[2][lc]+S[3][lc];
}

// ---------------- final: reward finalize + ns_new assembly ----------------

__global__ __launch_bounds__(256) void k_final(const float* __restrict__ rsp,
                                               const ushort* __restrict__ g,
                                               const float* __restrict__ ns,
                                               float* __restrict__ out) {
  int idx = blockIdx.x*256+threadIdx.x;
  if (idx < OUT_R_) {
    int b = idx / FSS_, c = idx - b*FSS_;
    float s = 0.f;
    #pragma unroll
    for (int z=0;z<8;z++) s += rsp[((size_t)z*B_ + b)*FSS_ + c];
    out[idx] = s;
  } else {
    int j2 = idx - OUT_R_;
    if (j2 >= B_*NSROW_) return;
    int b = j2 / NSROW_; int j = j2 - b*NSROW_;
    float v;
    if (j < SLEFT_) {
      int n = j >> 5, c = j & 31;
      v = b2f(g[(size_t)(b*N_+n)*HLD_ + 640 + c]);
    } else {
      v = ns[(size_t)b*NSROW_ + j];
    }
    out[idx] = v;
  }
}

// ---------------- host driver ----------------

extern "C" void kernel_launch(void* const* d_in, const int* in_sizes, int n_in,
                              void* d_out, int out_size, void* d_ws, size_t ws_size,
                              hipStream_t stream) {
  const float* ns = (const float*)d_in[0];
  const int*   a  = (const int*)d_in[1];

  const float *W[4], *As[4], *Ad[4], *Bb[4], *Sc[3], *Of[3];
  const float *rW[4], *rAs[4], *rAd[4], *rBb[4], *rSc[3], *rOf[3];
  int p = 2;
  for (int i=0;i<4;i++){
    W[i]=(const float*)d_in[p++]; As[i]=(const float*)d_in[p++];
    Ad[i]=(const float*)d_in[p++]; Bb[i]=(const float*)d_in[p++];
    if (i<3){ Sc[i]=(const float*)d_in[p++]; Of[i]=(const float*)d_in[p++]; }
  }
  for (int i=0;i<4;i++){
    rW[i]=(const float*)d_in[p++]; rAs[i]=(const float*)d_in[p++];
    rAd[i]=(const float*)d_in[p++]; rBb[i]=(const float*)d_in[p++];
    if (i<3){ rSc[i]=(const float*)d_in[p++]; rOf[i]=(const float*)d_in[p++]; }
  }

  char* w = (char*)d_ws;
  auto carve = [&](size_t bytes)->void* {
    void* r = (void*)w;
    w += (bytes + 255) & ~(size_t)255;
    return r;
  };
  ushort* hbuf = (ushort*)carve((size_t)BN_*HLD_*2);
  ushort* gbuf = (ushort*)carve((size_t)BN_*HLD_*2);
  ushort* sabf = (ushort*)carve((size_t)BN_*64*2);
  // zero-region: cnt | esed[4 layers] — one memset covers all
  int* cnt     = (int*)carve((size_t)(BN_ + 4*4*BN_)*4);
  float* esedL = (float*)(cnt + BN_);                // 4 x [4*BN]
  int* bins    = (int*)carve((size_t)BN_*CAP_*4);    // 4 MB
  float* stp   = (float*)carve((size_t)8*B_*HLD_*4);
  float* mulb  = (float*)carve((size_t)B_*KXB_*4);
  float* addb  = (float*)carve((size_t)B_*KXB_*4);
  float* rsp   = (float*)carve((size_t)8*B_*FSS_*4);
  ushort* Wt[4];
  Wt[0] = (ushort*)carve((size_t)768*64*2);
  Wt[1] = (ushort*)carve((size_t)768*736*2);
  Wt[2] = (ushort*)carve((size_t)768*672*2);
  Wt[3] = (ushort*)carve((size_t)768*672*2);

  float* out = (float*)d_out;

  hipMemsetAsync(cnt, 0, (size_t)(BN_ + 16*BN_)*4, stream);

  SetupP sp;
  sp.ns = ns; sp.a = a; sp.cnt = cnt; sp.bins = bins; sp.sa = sabf;
  for (int i=0;i<4;i++){ sp.Wr[i]=rW[i]; sp.Wn[i]=W[i]; sp.T[i]=Wt[i]; }
  k_setup<<<4167, 256, 0, stream>>>(sp);

  dim3 ggrid(6, BN_/64);   // 768 blocks

  int Kp[4]   = { 64, 736, 672, 672 };
  int dns[4]  = { 128, 64, 64, 32 };
  int kRe[4]  = { 64, 608, 608, 608 };
  int kNb[4]  = { 0, 608, 608, 608 };

  for (int L=0; L<4; ++L) {
    float* esed = esedL + (size_t)L*4*BN_;
    const ushort* Ain = (L==0) ? sabf : gbuf;
    k_gemm<<<ggrid, 256, 0, stream>>>(Ain, Wt[L], hbuf, esed,
                                      rAs[L], rAd[L], As[L], Ad[L],
                                      mulb, addb, Kp[L], dns[L],
                                      kRe[L], kNb[L], (L==0)?0:1);
    k_agg<<<BN_/4, 256, 0, stream>>>(hbuf, esed, cnt, bins,
                                     rBb[L], Bb[L], gbuf, dns[L]);
    if (L < 3) {
      k_ln_stats<<<dim3(12, B_, 4), 256, 0, stream>>>(gbuf, stp);
      k_stfin<<<dim3(3, B_), 256, 0, stream>>>(stp, rSc[L], rOf[L], Sc[L], Of[L],
                                               mulb, addb, dns[L]);
    }
  }

  k_rsum<<<dim3(10, B_, 8), 256, 0, stream>>>(gbuf, rsp);
  k_final<<<(OUT_R_ + B_*NSROW_ + 255)/256, 256, 0, stream>>>(rsp, gbuf, ns, out);
}